// Round 10
// baseline (811.855 us; speedup 1.0000x reference)
//
#include <hip/hip_runtime.h>
#include <hip/hip_bf16.h>

#define NN 50000   // nodes
#define NE 400000  // edges
#define DD 384     // input dim
#define HC 512     // heads * per-head dim (4 heads x 128)

typedef unsigned int u32;
typedef unsigned short u16;
typedef __attribute__((ext_vector_type(8))) short bf16x8;  // 8 bf16 (4 VGPRs)
typedef __attribute__((ext_vector_type(4))) float f32x4;

#define AS1 __attribute__((address_space(1)))
#define AS3 __attribute__((address_space(3)))

__device__ __forceinline__ float bflo(u32 u){ return __uint_as_float(u << 16); }
__device__ __forceinline__ float bfhi(u32 u){ return __uint_as_float(u & 0xFFFF0000u); }
__device__ __forceinline__ u16 f2bf(float f){
    u32 u = __float_as_uint(f);
    return (u16)((u + 0x7FFFu + ((u >> 16) & 1u)) >> 16);   // RNE
}
__device__ __forceinline__ u32 pack2(float a, float b){
    return (u32)f2bf(a) | ((u32)f2bf(b) << 16);
}

// ---------------------------------------------------------------------------
// Persistent weight-stationary QKVS GEMM, v3 — round-7-proven 4-wave engine.
// Grid = 256 blocks x 256 threads (4 waves 2x2, wave owns 64x64).
// W[ct*128..+128)[K] stationary in LDS wide rows (row stride K*2 ≡ 0 mod 128B,
// full 8-slot XOR pre-swizzle -> measured-0-conflict read pattern, r7).
// A panels stream through 2x16 KB dbuf, counted vmcnt(4) (~150-200-step pipe);
// vmcnt(20) on the step after an epilogue so the 16 fresh stores don't block.
// MFMA operands SWAPPED (bv, av): lane holds 4 consecutive output cols ->
// epilogue = 16 dwordx2 stores/wave (4x fewer store+pack instructions).
// ---------------------------------------------------------------------------
template<int K>
__global__ __launch_bounds__(256)
void gemm_ws(const u16* __restrict__ Ab, const u16* __restrict__ Wb,
             const float* __restrict__ bias,
             u16* __restrict__ oQ, u16* __restrict__ oK,
             u16* __restrict__ oV, u16* __restrict__ oS)
{
    constexpr int NKT  = K / 64;        // A k-chunks per panel (6 or 8)
    constexpr int WCH  = K / 8;         // 16B chunks per W row
    constexpr int NPAN = (NN + 127) / 128;
    __shared__ char smW[128 * K * 2];   // 96/128 KB wide rows
    __shared__ char smA[2][16384];      // [buf][128 rows][64k x 2B]

    const int b   = blockIdx.x;
    const int xcd = b & 7;
    const int idx = b >> 3;
    const int ct  = idx & 15;           // col-tile (128 of 2048)
    const int rh  = idx >> 4;           // row-half

    const int tid  = threadIdx.x;
    const int lane = tid & 63;
    const int w    = tid >> 6;
    const int wr   = w >> 1, wc = w & 1;
    const int r16  = lane & 15;
    const int kq   = lane >> 4;

    // ---- stage W once (gload_lds, source pre-swizzled per 128-B window) ----
    {
        const u16* W0 = Wb + (size_t)ct * 128 * K;
        #pragma unroll
        for (int p = 0; p < (128 * WCH) / 256; ++p) {
            int ci = p * 256 + tid;
            int row = ci / WCH, pc = ci % WCH;
            int lc = (pc & ~7) | ((pc ^ row) & 7);
            __builtin_amdgcn_global_load_lds((const AS1 u32*)(W0 + (size_t)row * K + lc * 8),
                                             (AS3 u32*)(smW + (size_t)ci * 16), 16, 0, 0);
        }
    }

    // ---- panel list p = (2j+rh)*8 + xcd (bijective over [0,391)) ----
    int np = 0;
    while ((2 * np + rh) * 8 + xcd < NPAN) ++np;     // 24 or 25
    const int total = np * NKT;

    auto stageA = [&](int t) {                       // 4 gload_lds / wave
        int jp = t / NKT, kc = t - jp * NKT;
        int m0 = ((2 * jp + rh) * 8 + xcd) * 128;
        #pragma unroll
        for (int p = 0; p < 4; ++p) {
            int ci = p * 256 + tid;
            int row = ci >> 3, pc = ci & 7;
            int lc = pc ^ (row & 7);
            int gr = m0 + row; if (gr >= NN) gr = NN - 1;
            __builtin_amdgcn_global_load_lds((const AS1 u32*)(Ab + (size_t)gr * K + kc * 64 + lc * 8),
                                             (AS3 u32*)(smA[t & 1] + ci * 16), 16, 0, 0);
        }
    };

    stageA(0);
    if (total > 1) stageA(1);

    f32x4 acc[4][4] = {};

    const int qsel = ct >> 2;
    u16* outp = (qsel == 0) ? oQ : (qsel == 1) ? oK : (qsel == 2) ? oV : oS;
    const int cb = (ct & 3) * 128 + wc * 64;
    float bb[4][4];
    #pragma unroll
    for (int ni = 0; ni < 4; ++ni)
        #pragma unroll
        for (int r = 0; r < 4; ++r)
            bb[ni][r] = bias[ct * 128 + wc * 64 + ni * 16 + kq * 4 + r];

    for (int t = 0; t < total; ++t) {
        const int jp = t / NKT, kc = t - jp * NKT;
        if (t + 1 >= total)                { asm volatile("s_waitcnt vmcnt(0)"  ::: "memory"); }
        else if (kc == 0 && t > 0)         { asm volatile("s_waitcnt vmcnt(20)" ::: "memory"); }
        else                               { asm volatile("s_waitcnt vmcnt(4)"  ::: "memory"); }
        __builtin_amdgcn_s_barrier();          // stage(t) landed for all waves
        __builtin_amdgcn_sched_barrier(0);

        const char* pa = smA[t & 1] + (wr * 64) * 128;
        #pragma unroll
        for (int kk = 0; kk < 2; ++kk) {
            const int slot = (((kk << 2) + kq) ^ (r16 & 7)) << 4;
            bf16x8 av[4], bv[4];
            #pragma unroll
            for (int i = 0; i < 4; ++i) {
                av[i] = *(const bf16x8*)(pa + (i * 16 + r16) * 128 + slot);
                int rw = wc * 64 + i * 16 + r16;
                bv[i] = *(const bf16x8*)(smW + (size_t)rw * (K * 2) + kc * 128 + slot);
            }
            #pragma unroll
            for (int mi = 0; mi < 4; ++mi)
                #pragma unroll
                for (int ni = 0; ni < 4; ++ni)
                    acc[mi][ni] = __builtin_amdgcn_mfma_f32_16x16x32_bf16(
                        bv[ni], av[mi], acc[mi][ni], 0, 0, 0);   // SWAPPED
        }

        __builtin_amdgcn_sched_barrier(0);
        __builtin_amdgcn_s_barrier();          // all waves done with buf t&1
        __builtin_amdgcn_sched_barrier(0);

        if (kc == NKT - 1) {                   // panel done: packed epilogue
            int m0 = ((2 * jp + rh) * 8 + xcd) * 128;
            #pragma unroll
            for (int mi = 0; mi < 4; ++mi) {
                int gr = m0 + wr * 64 + mi * 16 + r16;   // lane&15 -> row
                bool ok = gr < NN;
                #pragma unroll
                for (int ni = 0; ni < 4; ++ni) {
                    uint2 o;
                    o.x = pack2(acc[mi][ni][0] + bb[ni][0], acc[mi][ni][1] + bb[ni][1]);
                    o.y = pack2(acc[mi][ni][2] + bb[ni][2], acc[mi][ni][3] + bb[ni][3]);
                    if (ok) *(uint2*)(outp + (size_t)gr * 512 + cb + ni * 16 + kq * 4) = o;
                    #pragma unroll
                    for (int r = 0; r < 4; ++r) acc[mi][ni][r] = 0.f;
                }
            }
        }
        if (t + 2 < total) stageA(t + 2);      // overwrite now-free buffer
    }
}

// ---------------------------------------------------------------------------
// 2-deep pipelined MFMA GEMM — output projection (swapped-operand epilogue).
// ---------------------------------------------------------------------------
template<int K>
__global__ __launch_bounds__(256)
void gemm2ph(const u16* __restrict__ Ab, const u16* __restrict__ Wb,
             const float* __restrict__ bias, float* __restrict__ oF,
             int n, int Ototal, int NT)
{
    constexpr int NKT = K / 64;
    __shared__ char smA[2][16384];
    __shared__ char smB[2][16384];

    const int nb  = gridDim.x;
    const int bd  = blockIdx.x;
    const int q8  = nb >> 3, r8 = nb & 7;
    const int xcd = bd & 7, gg = bd >> 3;
    const int tt  = (xcd < r8 ? xcd * (q8 + 1) : r8 * (q8 + 1) + (xcd - r8) * q8) + gg;
    const int m0  = (tt / NT) * 128;
    const int o0  = (tt % NT) * 128;

    const int tid  = threadIdx.x;
    const int lane = tid & 63;
    const int w    = tid >> 6;
    const int wr   = w >> 1, wc = w & 1;
    const int r16  = lane & 15;
    const int kq   = lane >> 4;

    auto stage = [&](int bf, int kt) {
        #pragma unroll
        for (int p = 0; p < 4; ++p) {
            int ci = p * 256 + tid, row = ci >> 3, pc = ci & 7;
            int lc = pc ^ (row & 7);
            const u16* g = Wb + (size_t)(o0 + row) * K + kt * 64 + lc * 8;
            __builtin_amdgcn_global_load_lds((const AS1 u32*)g,
                                             (AS3 u32*)(smB[bf] + ci * 16), 16, 0, 0);
        }
        #pragma unroll
        for (int p = 0; p < 4; ++p) {
            int ci = p * 256 + tid, row = ci >> 3, pc = ci & 7;
            int lc = pc ^ (row & 7);
            int gr = m0 + row; if (gr >= n) gr = n - 1;
            const u16* g = Ab + (size_t)gr * K + kt * 64 + lc * 8;
            __builtin_amdgcn_global_load_lds((const AS1 u32*)g,
                                             (AS3 u32*)(smA[bf] + ci * 16), 16, 0, 0);
        }
    };

    f32x4 acc[4][4] = {};

    stage(0, 0);
    stage(1, 1);

    for (int kt = 0; kt < NKT; ++kt) {
        if (kt + 1 < NKT) { asm volatile("s_waitcnt vmcnt(8)" ::: "memory"); }
        else             { asm volatile("s_waitcnt vmcnt(0)" ::: "memory"); }
        __builtin_amdgcn_s_barrier();
        __builtin_amdgcn_sched_barrier(0);

        const char* pa = smA[kt & 1] + (wr * 64) * 128;
        const char* pb = smB[kt & 1] + (wc * 64) * 128;
        #pragma unroll
        for (int kk = 0; kk < 2; ++kk) {
            const int slot = (((kk << 2) + kq) ^ (r16 & 7)) << 4;
            bf16x8 av[4], bv[4];
            #pragma unroll
            for (int i = 0; i < 4; ++i) {
                av[i] = *(const bf16x8*)(pa + (i * 16 + r16) * 128 + kk * 0 + slot + 0);
                bv[i] = *(const bf16x8*)(pb + (i * 16 + r16) * 128 + slot);
            }
            #pragma unroll
            for (int mi = 0; mi < 4; ++mi)
                #pragma unroll
                for (int ni = 0; ni < 4; ++ni)
                    acc[mi][ni] = __builtin_amdgcn_mfma_f32_16x16x32_bf16(
                        bv[ni], av[mi], acc[mi][ni], 0, 0, 0);   // SWAPPED
        }

        __builtin_amdgcn_sched_barrier(0);
        __builtin_amdgcn_s_barrier();
        __builtin_amdgcn_sched_barrier(0);
        if (kt + 2 < NKT) stage(kt & 1, kt + 2);
    }

    #pragma unroll
    for (int mi = 0; mi < 4; ++mi) {
        int gr = m0 + wr * 64 + mi * 16 + r16;
        if (gr >= n) continue;
        #pragma unroll
        for (int ni = 0; ni < 4; ++ni) {
            int col = o0 + wc * 64 + ni * 16 + kq * 4;
            float4 o = make_float4(acc[mi][ni][0] + bias[col],
                                   acc[mi][ni][1] + bias[col + 1],
                                   acc[mi][ni][2] + bias[col + 2],
                                   acc[mi][ni][3] + bias[col + 3]);
            *(float4*)(oF + (size_t)gr * Ototal + col) = o;
        }
    }
}

// ---------------------------------------------------------------------------
// Fused fp32 -> bf16 conversion of x + all 9 weight matrices (one launch).
#define XG  2400000      // 50000*384/8
#define W0G 24576        // 512*384/8 per matrix
#define W1G 32768        // 512*512/8 per matrix
#define WOG 24576        // 384*512/8
#define CVT_TOTAL (XG + 4*W0G + 4*W1G + WOG)

__global__ __launch_bounds__(256)
void cvt_all(const float* __restrict__ x,
             const float* q0w, const float* k0w, const float* v0w, const float* s0w,
             const float* q1w, const float* k1w, const float* v1w, const float* s1w,
             const float* ow,
             u16* __restrict__ Xb, u16* __restrict__ Wc0,
             u16* __restrict__ Wc1, u16* __restrict__ WcO)
{
    int i = blockIdx.x * 256 + threadIdx.x;
    if (i >= CVT_TOTAL) return;
    const float* s; u16* d; int g;
    if (i < XG) { s = x; d = Xb; g = i; }
    else {
        int j = i - XG;
        if (j < 4 * W0G) {
            int q = j / W0G; g = j - q * W0G;
            s = (q == 0 ? q0w : q == 1 ? k0w : q == 2 ? v0w : s0w);
            d = Wc0 + (size_t)q * W0G * 8;
        } else if ((j -= 4 * W0G) < 4 * W1G) {
            int q = j / W1G; g = j - q * W1G;
            s = (q == 0 ? q1w : q == 1 ? k1w : q == 2 ? v1w : s1w);
            d = Wc1 + (size_t)q * W1G * 8;
        } else { j -= 4 * W1G; s = ow; d = WcO; g = j; }
    }
    float4 f0 = ((const float4*)s)[(size_t)g * 2];
    float4 f1 = ((const float4*)s)[(size_t)g * 2 + 1];
    uint4 o;
    o.x = pack2(f0.x, f0.y); o.y = pack2(f0.z, f0.w);
    o.z = pack2(f1.x, f1.y); o.w = pack2(f1.z, f1.w);
    ((uint4*)d)[g] = o;
}

// bias arena: [0..2047]=layer0 qkvs, [2048..4095]=layer1 qkvs, [4096..4479]=out
__global__ __launch_bounds__(256)
void pack_bias(const float* q0, const float* k0, const float* v0, const float* s0,
               const float* q1, const float* k1, const float* v1, const float* s1,
               const float* ob, float* __restrict__ dst)
{
    int i = blockIdx.x * 256 + threadIdx.x;
    if (i >= 4480) return;
    float v;
    if (i < 2048) {
        int j = i & 511, q = i >> 9;
        v = (q == 0 ? q0 : q == 1 ? k0 : q == 2 ? v0 : s0)[j];
    } else if (i < 4096) {
        int j = i - 2048; int q = j >> 9; j &= 511;
        v = (q == 0 ? q1 : q == 1 ? k1 : q == 2 ? v1 : s1)[j];
    } else {
        v = ob[i - 4096];
    }
    dst[i] = v;
}

// ---------------------------------------------------------------------------
// CSR build (order within bucket nondeterministic -> only permutes fp adds)
// ---------------------------------------------------------------------------
__global__ __launch_bounds__(256)
void zero_deg(int* __restrict__ deg)
{
    int i = blockIdx.x * 256 + threadIdx.x;
    if (i < NN) deg[i] = 0;
}

__global__ __launch_bounds__(256)
void hist_dst(const int* __restrict__ dst, int* __restrict__ deg)
{
    int e = blockIdx.x * 256 + threadIdx.x;
    if (e < NE) atomicAdd(&deg[dst[e]], 1);
}

// single-block scan, wave-shfl based
__global__ __launch_bounds__(1024)
void scan_deg(const int* __restrict__ deg, int* __restrict__ rowptr,
              int* __restrict__ cursor)
{
    __shared__ int wsum[16];
    const int tid = threadIdx.x, lane = tid & 63, wid = tid >> 6;
    int carry = 0;
    for (int base = 0; base < NN; base += 1024) {
        int i = base + tid;
        int orig = (i < NN) ? deg[i] : 0;
        int v = orig;
        #pragma unroll
        for (int off = 1; off < 64; off <<= 1) {
            int t = __shfl_up(v, off, 64);
            if (lane >= off) v += t;
        }
        if (lane == 63) wsum[wid] = v;
        __syncthreads();
        if (wid == 0) {
            int s = (lane < 16) ? wsum[lane] : 0;
            #pragma unroll
            for (int off = 1; off < 16; off <<= 1) {
                int t = __shfl_up(s, off, 16);
                if ((lane & 15) >= off) s += t;
            }
            if (lane < 16) wsum[lane] = s;
        }
        __syncthreads();
        int woff  = (wid == 0) ? 0 : wsum[wid - 1];
        int total = wsum[15];
        int excl  = carry + woff + (v - orig);
        if (i < NN) { rowptr[i] = excl; cursor[i] = excl; }
        carry += total;
        __syncthreads();
    }
    if (tid == 0) rowptr[NN] = NE;
}

__global__ __launch_bounds__(256)
void scatter_edges(const int* __restrict__ src, const int* __restrict__ dst,
                   int* __restrict__ cursor, int* __restrict__ esrc_ord)
{
    int e = blockIdx.x * 256 + threadIdx.x;
    if (e >= NE) return;
    int pos = atomicAdd(&cursor[dst[e]], 1);
    esrc_ord[pos] = src[e];
}

// ---------------------------------------------------------------------------
// Fused per-node attention: one 64-lane wave per dst node; online softmax.
// ---------------------------------------------------------------------------
__global__ __launch_bounds__(256)
void node_attn(const u16* __restrict__ Qb, const u16* __restrict__ Kb,
               const u16* __restrict__ Vb, const int* __restrict__ rowptr,
               const int* __restrict__ esrc, const u16* __restrict__ skipb,
               u16* __restrict__ outb)
{
    int d = blockIdx.x * 4 + (threadIdx.x >> 6);
    if (d >= NN) return;
    int lane = threadIdx.x & 63;

    uint4 qv = *((const uint4*)(Qb + (size_t)d * HC) + lane);
    float q[8] = { bflo(qv.x), bfhi(qv.x), bflo(qv.y), bfhi(qv.y),
                   bflo(qv.z), bfhi(qv.z), bflo(qv.w), bfhi(qv.w) };

    int beg = rowptr[d], end = rowptr[d + 1];
    float m = -INFINITY, den = 0.f;
    float acc[8] = {};

    for (int i = beg; i < end; ++i) {
        int s = esrc[i];
        uint4 kv = *((const uint4*)(Kb + (size_t)s * HC) + lane);
        float sum = q[0] * bflo(kv.x) + q[1] * bfhi(kv.x)
                  + q[2] * bflo(kv.y) + q[3] * bfhi(kv.y)
                  + q[4] * bflo(kv.z) + q[5] * bfhi(kv.z)
                  + q[6] * bflo(kv.w) + q[7] * bfhi(kv.w);
        #pragma unroll
        for (int off = 1; off < 16; off <<= 1) sum += __shfl_xor(sum, off, 64);
        float alpha = sum * 0.08838834764831845f;

        float mnew  = fmaxf(m, alpha);
        float scale = __expf(m - mnew);      // first edge: exp(-inf)=0
        float p     = __expf(alpha - mnew);
        den = den * scale + p;

        uint4 vv = *((const uint4*)(Vb + (size_t)s * HC) + lane);
        acc[0] = acc[0] * scale + p * bflo(vv.x);
        acc[1] = acc[1] * scale + p * bfhi(vv.x);
        acc[2] = acc[2] * scale + p * bflo(vv.y);
        acc[3] = acc[3] * scale + p * bfhi(vv.y);
        acc[4] = acc[4] * scale + p * bflo(vv.z);
        acc[5] = acc[5] * scale + p * bfhi(vv.z);
        acc[6] = acc[6] * scale + p * bflo(vv.w);
        acc[7] = acc[7] * scale + p * bfhi(vv.w);
        m = mnew;
    }

    float inv = 1.f / (den + 1e-16f);
    size_t base = (size_t)d * HC + lane * 8;
    uint4 sv = *((const uint4*)(skipb + base));
    float sk[8] = { bflo(sv.x), bfhi(sv.x), bflo(sv.y), bfhi(sv.y),
                    bflo(sv.z), bfhi(sv.z), bflo(sv.w), bfhi(sv.w) };
    uint4 o;
    o.x = pack2(fmaxf(acc[0] * inv + sk[0], 0.f), fmaxf(acc[1] * inv + sk[1], 0.f));
    o.y = pack2(fmaxf(acc[2] * inv + sk[2], 0.f), fmaxf(acc[3] * inv + sk[3], 0.f));
    o.z = pack2(fmaxf(acc[4] * inv + sk[4], 0.f), fmaxf(acc[5] * inv + sk[5], 0.f));
    o.w = pack2(fmaxf(acc[6] * inv + sk[6], 0.f), fmaxf(acc[7] * inv + sk[7], 0.f));
    *(uint4*)(outb + base) = o;
}

// ---------------------------------------------------------------------------
extern "C" void kernel_launch(void* const* d_in, const int* in_sizes, int n_in,
                              void* d_out, int out_size, void* d_ws, size_t ws_size,
                              hipStream_t stream)
{
    const float* x   = (const float*)d_in[0];
    const int* ei    = (const int*)d_in[1];
    const int* esrc  = ei;
    const int* edst  = ei + NE;
    const float* q0w = (const float*)d_in[2];  const float* q0b = (const float*)d_in[3];
    const float* k0w = (const float*)d_in[4];  const float* k0b = (const float*)d_in[5];
    const float* v0w = (const float*)d_in[6];  const float* v0b = (const float*)d_in[7];
    const float* s0w = (const float*)d_in[8];  const float* s0b = (const float*)d_in[9];
    const float* q1w = (const float*)d_in[10]; const float* q1b = (const float*)d_in[11];
    const float* k1w = (const float*)d_in[12]; const float* k1b = (const float*)d_in[13];
    const float* v1w = (const float*)d_in[14]; const float* v1b = (const float*)d_in[15];
    const float* s1w = (const float*)d_in[16]; const float* s1b = (const float*)d_in[17];
    const float* ow  = (const float*)d_in[18]; const float* obs = (const float*)d_in[19];

    // ---- workspace (~247 MB) ----
    char* p = (char*)d_ws;
    auto take = [&](size_t bytes) { void* r = (void*)p; p += (bytes + 255) & ~(size_t)255; return r; };
    u16*   Qb     = (u16*)take((size_t)NN * HC * 2);       // 51.2 MB
    u16*   Vb     = (u16*)take((size_t)NN * HC * 2);       // 51.2 MB
    u16*   Hb     = (u16*)take((size_t)NN * HC * 2);       // 51.2 MB
    u16*   Sb     = (u16*)take((size_t)NN * HC * 2);       // 51.2 MB (bf16 skip)
    u16*   Xb     = (u16*)take((size_t)NN * DD * 2);       // 38.4 MB (bf16 x)
    u16*   Wc0    = (u16*)take((size_t)2048 * DD * 2);     // 1.57 MB
    u16*   Wc1    = (u16*)take((size_t)2048 * HC * 2);     // 2.10 MB
    u16*   WcO    = (u16*)take((size_t)DD * HC * 2);       // 0.39 MB
    float* barena = (float*)take(4480 * 4);                // 17.9 KB

    // ---- scratch carved from d_out (dead before final GEMM overwrites all) ----
    char* dob = (char*)d_out;
    u16* Kb       = (u16*)dob;                             // 51.2 MB
    int* deg      = (int*)(dob + 51200000);
    int* rowptr   = (int*)(dob + 51400192);                // NN+1
    int* cursor   = (int*)(dob + 51600384);
    int* esrc_ord = (int*)(dob + 51800576);                // 1.6 MB

    dim3 blk(256);
    int gN   = (NN + 255) / 256;
    int gE   = (NE + 255) / 256;
    int gnod = (NN + 3) / 4;
    const int NPAN = (NN + 127) / 128;   // 391 row panels
    int go = NPAN * 3;                   // out-proj: 3 col-tiles

    // ---- prep (2 launches) ----
    pack_bias<<<(4480 + 255) / 256, blk, 0, stream>>>(q0b, k0b, v0b, s0b,
                                                      q1b, k1b, v1b, s1b, obs, barena);
    cvt_all<<<(CVT_TOTAL + 255) / 256, blk, 0, stream>>>(x,
        q0w, k0w, v0w, s0w, q1w, k1w, v1w, s1w, ow, Xb, Wc0, Wc1, WcO);

    // ---- CSR build ----
    zero_deg      <<<gN, blk, 0, stream>>>(deg);
    hist_dst      <<<gE, blk, 0, stream>>>(edst, deg);
    scan_deg      <<<1, 1024, 0, stream>>>(deg, rowptr, cursor);
    scatter_edges <<<gE, blk, 0, stream>>>(esrc, edst, cursor, esrc_ord);

    // ---- layer 0 (A = Xb bf16, K=384) ----
    gemm_ws<DD><<<256, 256, 0, stream>>>(Xb, Wc0, barena, Qb, Kb, Vb, Sb);
    node_attn<<<gnod, blk, 0, stream>>>(Qb, Kb, Vb, rowptr, esrc_ord, Sb, Hb);

    // ---- layer 1 (A = Hb bf16, K=512) ----
    gemm_ws<HC><<<256, 256, 0, stream>>>(Hb, Wc1, barena + 2048, Qb, Kb, Vb, Sb);
    node_attn<<<gnod, blk, 0, stream>>>(Qb, Kb, Vb, rowptr, esrc_ord, Sb, Hb);

    // ---- output projection (fp32 out, overwrites ALL of d_out) ----
    gemm2ph<HC><<<go, blk, 0, stream>>>(Hb, WcO, barena + 4096,
                                        (float*)d_out, NN, 384, 3);
}

// Round 11
// 792.323 us; speedup vs baseline: 1.0247x; 1.0247x over previous
//
#include <hip/hip_runtime.h>
#include <hip/hip_bf16.h>

#define NN 50000   // nodes
#define NE 400000  // edges
#define DD 384     // input dim
#define HC 512     // heads * per-head dim (4 heads x 128)

typedef unsigned int u32;
typedef unsigned short u16;
typedef __attribute__((ext_vector_type(8))) short bf16x8;  // 8 bf16 (4 VGPRs)
typedef __attribute__((ext_vector_type(4))) float f32x4;

#define AS1 __attribute__((address_space(1)))
#define AS3 __attribute__((address_space(3)))

__device__ __forceinline__ float bflo(u32 u){ return __uint_as_float(u << 16); }
__device__ __forceinline__ float bfhi(u32 u){ return __uint_as_float(u & 0xFFFF0000u); }
__device__ __forceinline__ u16 f2bf(float f){
    u32 u = __float_as_uint(f);
    return (u16)((u + 0x7FFFu + ((u >> 16) & 1u)) >> 16);   // RNE
}
__device__ __forceinline__ u32 pack2(float a, float b){
    return (u32)f2bf(a) | ((u32)f2bf(b) << 16);
}

// ---------------------------------------------------------------------------
// Persistent weight-stationary QKVS GEMM — r8 geometry (best measured: 176us)
// + r10's swapped-operand packed epilogue + store-aware counted vmcnt.
// Grid = 256 blocks x 512 threads (8 waves: wq=row-quarter 0..3, wc=col-half).
// W[ct*128..+128)[K] stationary in LDS wide rows, 8-slot XOR per 128-B window.
// A panels stream through 2x16 KB dbuf, vmcnt(2) steady / vmcnt(10) after an
// epilogue (8 uint2 stores/thread count in vmcnt — don't wait for them).
// MFMA operands swapped (bv,av): lane&15 = output row, kq*4+r = output col ->
// epilogue packs 4 cols into one dwordx2, 8 stores/thread (was 32 scalar u16).
// ---------------------------------------------------------------------------
template<int K>
__global__ __launch_bounds__(512)
void gemm_ws(const u16* __restrict__ Ab, const u16* __restrict__ Wb,
             const float* __restrict__ bias,
             u16* __restrict__ oQ, u16* __restrict__ oK,
             u16* __restrict__ oV, u16* __restrict__ oS)
{
    constexpr int NKT  = K / 64;        // A k-chunks per panel (6 or 8)
    constexpr int WCH  = K / 8;         // 16B chunks per W row
    constexpr int NPAN = (NN + 127) / 128;
    __shared__ char smW[128 * K * 2];   // 96/128 KB wide rows
    __shared__ char smA[2][16384];      // [buf][128 rows][64k x 2B]

    const int b   = blockIdx.x;
    const int xcd = b & 7;
    const int idx = b >> 3;
    const int ct  = idx & 15;           // col-tile (128 of 2048)
    const int rh  = idx >> 4;           // row-half

    const int tid  = threadIdx.x;
    const int lane = tid & 63;
    const int w    = tid >> 6;
    const int wq   = w >> 1;            // row quarter (32 rows)
    const int wc   = w & 1;             // col half (64 cols)
    const int r16  = lane & 15;
    const int kq   = lane >> 4;

    // ---- stage W once (gload_lds, source pre-swizzled per 128-B window) ----
    {
        const u16* W0 = Wb + (size_t)ct * 128 * K;
        #pragma unroll
        for (int p = 0; p < (128 * WCH) / 512; ++p) {
            int ci = p * 512 + tid;
            int row = ci / WCH, pc = ci % WCH;
            int lc = (pc & ~7) | ((pc ^ row) & 7);
            __builtin_amdgcn_global_load_lds((const AS1 u32*)(W0 + (size_t)row * K + lc * 8),
                                             (AS3 u32*)(smW + (size_t)ci * 16), 16, 0, 0);
        }
    }

    // ---- panel list p = (2j+rh)*8 + xcd (bijective over [0,391)) ----
    int np = 0;
    while ((2 * np + rh) * 8 + xcd < NPAN) ++np;     // 24 or 25
    const int total = np * NKT;

    auto stageA = [&](int t) {                       // 2 gload_lds / thread
        int jp = t / NKT, kc = t - jp * NKT;
        int m0 = ((2 * jp + rh) * 8 + xcd) * 128;
        #pragma unroll
        for (int p = 0; p < 2; ++p) {
            int ci = p * 512 + tid;
            int row = ci >> 3, pc = ci & 7;
            int lc = pc ^ (row & 7);
            int gr = m0 + row; if (gr >= NN) gr = NN - 1;
            __builtin_amdgcn_global_load_lds((const AS1 u32*)(Ab + (size_t)gr * K + kc * 64 + lc * 8),
                                             (AS3 u32*)(smA[t & 1] + ci * 16), 16, 0, 0);
        }
    };

    stageA(0);
    if (total > 1) stageA(1);

    f32x4 acc[2][4] = {};

    const int qsel = ct >> 2;
    u16* outp = (qsel == 0) ? oQ : (qsel == 1) ? oK : (qsel == 2) ? oV : oS;
    const int cb = (ct & 3) * 128 + wc * 64;
    float bb[4][4];
    #pragma unroll
    for (int ni = 0; ni < 4; ++ni)
        #pragma unroll
        for (int r = 0; r < 4; ++r)
            bb[ni][r] = bias[ct * 128 + wc * 64 + ni * 16 + kq * 4 + r];

    for (int t = 0; t < total; ++t) {
        const int jp = t / NKT, kc = t - jp * NKT;
        if (t + 1 >= total)        { asm volatile("s_waitcnt vmcnt(0)"  ::: "memory"); }
        else if (kc == 0 && t > 0) { asm volatile("s_waitcnt vmcnt(10)" ::: "memory"); }
        else                       { asm volatile("s_waitcnt vmcnt(2)"  ::: "memory"); }
        __builtin_amdgcn_s_barrier();          // stage(t) landed for all waves
        __builtin_amdgcn_sched_barrier(0);

        const char* bufA = smA[t & 1];
        #pragma unroll
        for (int kk = 0; kk < 2; ++kk) {
            const int slot = (((kk << 2) + kq) ^ (r16 & 7)) << 4;
            bf16x8 av[2], bv[4];
            #pragma unroll
            for (int i = 0; i < 2; ++i)
                av[i] = *(const bf16x8*)(bufA + (wq * 32 + i * 16 + r16) * 128 + slot);
            #pragma unroll
            for (int i = 0; i < 4; ++i) {
                int rw = wc * 64 + i * 16 + r16;
                bv[i] = *(const bf16x8*)(smW + (size_t)rw * (K * 2) + kc * 128 + slot);
            }
            #pragma unroll
            for (int mi = 0; mi < 2; ++mi)
                #pragma unroll
                for (int ni = 0; ni < 4; ++ni)
                    acc[mi][ni] = __builtin_amdgcn_mfma_f32_16x16x32_bf16(
                        bv[ni], av[mi], acc[mi][ni], 0, 0, 0);   // SWAPPED
        }

        __builtin_amdgcn_sched_barrier(0);
        __builtin_amdgcn_s_barrier();          // all waves done with buf t&1
        __builtin_amdgcn_sched_barrier(0);

        if (kc == NKT - 1) {                   // panel done: packed epilogue
            int m0 = ((2 * jp + rh) * 8 + xcd) * 128;
            #pragma unroll
            for (int mi = 0; mi < 2; ++mi) {
                int gr = m0 + wq * 32 + mi * 16 + r16;   // r16 -> output row
                bool ok = gr < NN;
                #pragma unroll
                for (int ni = 0; ni < 4; ++ni) {
                    uint2 o;
                    o.x = pack2(acc[mi][ni][0] + bb[ni][0], acc[mi][ni][1] + bb[ni][1]);
                    o.y = pack2(acc[mi][ni][2] + bb[ni][2], acc[mi][ni][3] + bb[ni][3]);
                    if (ok) *(uint2*)(outp + (size_t)gr * 512 + cb + ni * 16 + kq * 4) = o;
                    #pragma unroll
                    for (int r = 0; r < 4; ++r) acc[mi][ni][r] = 0.f;
                }
            }
        }
        if (t + 2 < total) stageA(t + 2);      // overwrite now-free buffer
    }
}

// ---------------------------------------------------------------------------
// 2-deep pipelined MFMA GEMM — output projection (swapped, float4 epilogue).
// ---------------------------------------------------------------------------
template<int K>
__global__ __launch_bounds__(256)
void gemm2ph(const u16* __restrict__ Ab, const u16* __restrict__ Wb,
             const float* __restrict__ bias, float* __restrict__ oF,
             int n, int Ototal, int NT)
{
    constexpr int NKT = K / 64;
    __shared__ char smA[2][16384];
    __shared__ char smB[2][16384];

    const int nb  = gridDim.x;
    const int bd  = blockIdx.x;
    const int q8  = nb >> 3, r8 = nb & 7;
    const int xcd = bd & 7, gg = bd >> 3;
    const int tt  = (xcd < r8 ? xcd * (q8 + 1) : r8 * (q8 + 1) + (xcd - r8) * q8) + gg;
    const int m0  = (tt / NT) * 128;
    const int o0  = (tt % NT) * 128;

    const int tid  = threadIdx.x;
    const int lane = tid & 63;
    const int w    = tid >> 6;
    const int wr   = w >> 1, wc = w & 1;
    const int r16  = lane & 15;
    const int kq   = lane >> 4;

    auto stage = [&](int bf, int kt) {
        #pragma unroll
        for (int p = 0; p < 4; ++p) {
            int ci = p * 256 + tid, row = ci >> 3, pc = ci & 7;
            int lc = pc ^ (row & 7);
            const u16* g = Wb + (size_t)(o0 + row) * K + kt * 64 + lc * 8;
            __builtin_amdgcn_global_load_lds((const AS1 u32*)g,
                                             (AS3 u32*)(smB[bf] + ci * 16), 16, 0, 0);
        }
        #pragma unroll
        for (int p = 0; p < 4; ++p) {
            int ci = p * 256 + tid, row = ci >> 3, pc = ci & 7;
            int lc = pc ^ (row & 7);
            int gr = m0 + row; if (gr >= n) gr = n - 1;
            const u16* g = Ab + (size_t)gr * K + kt * 64 + lc * 8;
            __builtin_amdgcn_global_load_lds((const AS1 u32*)g,
                                             (AS3 u32*)(smA[bf] + ci * 16), 16, 0, 0);
        }
    };

    f32x4 acc[4][4] = {};

    stage(0, 0);
    stage(1, 1);

    for (int kt = 0; kt < NKT; ++kt) {
        if (kt + 1 < NKT) { asm volatile("s_waitcnt vmcnt(8)" ::: "memory"); }
        else             { asm volatile("s_waitcnt vmcnt(0)" ::: "memory"); }
        __builtin_amdgcn_s_barrier();
        __builtin_amdgcn_sched_barrier(0);

        const char* pa = smA[kt & 1] + (wr * 64) * 128;
        const char* pb = smB[kt & 1] + (wc * 64) * 128;
        #pragma unroll
        for (int kk = 0; kk < 2; ++kk) {
            const int slot = (((kk << 2) + kq) ^ (r16 & 7)) << 4;
            bf16x8 av[4], bv[4];
            #pragma unroll
            for (int i = 0; i < 4; ++i) {
                av[i] = *(const bf16x8*)(pa + (i * 16 + r16) * 128 + slot);
                bv[i] = *(const bf16x8*)(pb + (i * 16 + r16) * 128 + slot);
            }
            #pragma unroll
            for (int mi = 0; mi < 4; ++mi)
                #pragma unroll
                for (int ni = 0; ni < 4; ++ni)
                    acc[mi][ni] = __builtin_amdgcn_mfma_f32_16x16x32_bf16(
                        bv[ni], av[mi], acc[mi][ni], 0, 0, 0);   // SWAPPED
        }

        __builtin_amdgcn_sched_barrier(0);
        __builtin_amdgcn_s_barrier();
        __builtin_amdgcn_sched_barrier(0);
        if (kt + 2 < NKT) stage(kt & 1, kt + 2);
    }

    #pragma unroll
    for (int mi = 0; mi < 4; ++mi) {
        int gr = m0 + wr * 64 + mi * 16 + r16;
        if (gr >= n) continue;
        #pragma unroll
        for (int ni = 0; ni < 4; ++ni) {
            int col = o0 + wc * 64 + ni * 16 + kq * 4;
            float4 o = make_float4(acc[mi][ni][0] + bias[col],
                                   acc[mi][ni][1] + bias[col + 1],
                                   acc[mi][ni][2] + bias[col + 2],
                                   acc[mi][ni][3] + bias[col + 3]);
            *(float4*)(oF + (size_t)gr * Ototal + col) = o;
        }
    }
}

// ---------------------------------------------------------------------------
// Fused fp32 -> bf16 conversion of x + all 9 weight matrices (one launch).
#define XG  2400000      // 50000*384/8
#define W0G 24576        // 512*384/8 per matrix
#define W1G 32768        // 512*512/8 per matrix
#define WOG 24576        // 384*512/8
#define CVT_TOTAL (XG + 4*W0G + 4*W1G + WOG)

__global__ __launch_bounds__(256)
void cvt_all(const float* __restrict__ x,
             const float* q0w, const float* k0w, const float* v0w, const float* s0w,
             const float* q1w, const float* k1w, const float* v1w, const float* s1w,
             const float* ow,
             u16* __restrict__ Xb, u16* __restrict__ Wc0,
             u16* __restrict__ Wc1, u16* __restrict__ WcO)
{
    int i = blockIdx.x * 256 + threadIdx.x;
    if (i >= CVT_TOTAL) return;
    const float* s; u16* d; int g;
    if (i < XG) { s = x; d = Xb; g = i; }
    else {
        int j = i - XG;
        if (j < 4 * W0G) {
            int q = j / W0G; g = j - q * W0G;
            s = (q == 0 ? q0w : q == 1 ? k0w : q == 2 ? v0w : s0w);
            d = Wc0 + (size_t)q * W0G * 8;
        } else if ((j -= 4 * W0G) < 4 * W1G) {
            int q = j / W1G; g = j - q * W1G;
            s = (q == 0 ? q1w : q == 1 ? k1w : q == 2 ? v1w : s1w);
            d = Wc1 + (size_t)q * W1G * 8;
        } else { j -= 4 * W1G; s = ow; d = WcO; g = j; }
    }
    float4 f0 = ((const float4*)s)[(size_t)g * 2];
    float4 f1 = ((const float4*)s)[(size_t)g * 2 + 1];
    uint4 o;
    o.x = pack2(f0.x, f0.y); o.y = pack2(f0.z, f0.w);
    o.z = pack2(f1.x, f1.y); o.w = pack2(f1.z, f1.w);
    ((uint4*)d)[g] = o;
}

// bias arena: [0..2047]=layer0 qkvs, [2048..4095]=layer1 qkvs, [4096..4479]=out
__global__ __launch_bounds__(256)
void pack_bias(const float* q0, const float* k0, const float* v0, const float* s0,
               const float* q1, const float* k1, const float* v1, const float* s1,
               const float* ob, float* __restrict__ dst)
{
    int i = blockIdx.x * 256 + threadIdx.x;
    if (i >= 4480) return;
    float v;
    if (i < 2048) {
        int j = i & 511, q = i >> 9;
        v = (q == 0 ? q0 : q == 1 ? k0 : q == 2 ? v0 : s0)[j];
    } else if (i < 4096) {
        int j = i - 2048; int q = j >> 9; j &= 511;
        v = (q == 0 ? q1 : q == 1 ? k1 : q == 2 ? v1 : s1)[j];
    } else {
        v = ob[i - 4096];
    }
    dst[i] = v;
}

// ---------------------------------------------------------------------------
// CSR build (order within bucket nondeterministic -> only permutes fp adds)
// ---------------------------------------------------------------------------
__global__ __launch_bounds__(256)
void zero_deg(int* __restrict__ deg)
{
    int i = blockIdx.x * 256 + threadIdx.x;
    if (i < NN) deg[i] = 0;
}

__global__ __launch_bounds__(256)
void hist_dst(const int* __restrict__ dst, int* __restrict__ deg)
{
    int e = blockIdx.x * 256 + threadIdx.x;
    if (e < NE) atomicAdd(&deg[dst[e]], 1);
}

// single-block scan, wave-shfl based
__global__ __launch_bounds__(1024)
void scan_deg(const int* __restrict__ deg, int* __restrict__ rowptr,
              int* __restrict__ cursor)
{
    __shared__ int wsum[16];
    const int tid = threadIdx.x, lane = tid & 63, wid = tid >> 6;
    int carry = 0;
    for (int base = 0; base < NN; base += 1024) {
        int i = base + tid;
        int orig = (i < NN) ? deg[i] : 0;
        int v = orig;
        #pragma unroll
        for (int off = 1; off < 64; off <<= 1) {
            int t = __shfl_up(v, off, 64);
            if (lane >= off) v += t;
        }
        if (lane == 63) wsum[wid] = v;
        __syncthreads();
        if (wid == 0) {
            int s = (lane < 16) ? wsum[lane] : 0;
            #pragma unroll
            for (int off = 1; off < 16; off <<= 1) {
                int t = __shfl_up(s, off, 16);
                if ((lane & 15) >= off) s += t;
            }
            if (lane < 16) wsum[lane] = s;
        }
        __syncthreads();
        int woff  = (wid == 0) ? 0 : wsum[wid - 1];
        int total = wsum[15];
        int excl  = carry + woff + (v - orig);
        if (i < NN) { rowptr[i] = excl; cursor[i] = excl; }
        carry += total;
        __syncthreads();
    }
    if (tid == 0) rowptr[NN] = NE;
}

__global__ __launch_bounds__(256)
void scatter_edges(const int* __restrict__ src, const int* __restrict__ dst,
                   int* __restrict__ cursor, int* __restrict__ esrc_ord)
{
    int e = blockIdx.x * 256 + threadIdx.x;
    if (e >= NE) return;
    int pos = atomicAdd(&cursor[dst[e]], 1);
    esrc_ord[pos] = src[e];
}

// ---------------------------------------------------------------------------
// Fused per-node attention with 1-edge software prefetch: one wave per dst
// node; online softmax; lane owns 8 channels, 16-lane group = one head.
// K/V rows of edge i+1 are loaded while edge i computes (branch is
// wave-uniform: d, beg, end identical across the wave).
// ---------------------------------------------------------------------------
__global__ __launch_bounds__(256)
void node_attn(const u16* __restrict__ Qb, const u16* __restrict__ Kb,
               const u16* __restrict__ Vb, const int* __restrict__ rowptr,
               const int* __restrict__ esrc, const u16* __restrict__ skipb,
               u16* __restrict__ outb)
{
    int d = blockIdx.x * 4 + (threadIdx.x >> 6);
    if (d >= NN) return;
    int lane = threadIdx.x & 63;

    uint4 qv = *((const uint4*)(Qb + (size_t)d * HC) + lane);
    float q[8] = { bflo(qv.x), bfhi(qv.x), bflo(qv.y), bfhi(qv.y),
                   bflo(qv.z), bfhi(qv.z), bflo(qv.w), bfhi(qv.w) };

    int beg = rowptr[d], end = rowptr[d + 1];
    float m = -INFINITY, den = 0.f;
    float acc[8] = {};

    if (beg < end) {
        int s0 = esrc[beg];
        uint4 kv = *((const uint4*)(Kb + (size_t)s0 * HC) + lane);
        uint4 vv = *((const uint4*)(Vb + (size_t)s0 * HC) + lane);

        for (int i = beg; i < end; ++i) {
            uint4 kc = kv, vc = vv;
            if (i + 1 < end) {                   // prefetch next edge's rows
                int sn = esrc[i + 1];
                kv = *((const uint4*)(Kb + (size_t)sn * HC) + lane);
                vv = *((const uint4*)(Vb + (size_t)sn * HC) + lane);
            }
            float sum = q[0] * bflo(kc.x) + q[1] * bfhi(kc.x)
                      + q[2] * bflo(kc.y) + q[3] * bfhi(kc.y)
                      + q[4] * bflo(kc.z) + q[5] * bfhi(kc.z)
                      + q[6] * bflo(kc.w) + q[7] * bfhi(kc.w);
            #pragma unroll
            for (int off = 1; off < 16; off <<= 1) sum += __shfl_xor(sum, off, 64);
            float alpha = sum * 0.08838834764831845f;

            float mnew  = fmaxf(m, alpha);
            float scale = __expf(m - mnew);      // first edge: exp(-inf)=0
            float p     = __expf(alpha - mnew);
            den = den * scale + p;

            acc[0] = acc[0] * scale + p * bflo(vc.x);
            acc[1] = acc[1] * scale + p * bfhi(vc.x);
            acc[2] = acc[2] * scale + p * bflo(vc.y);
            acc[3] = acc[3] * scale + p * bfhi(vc.y);
            acc[4] = acc[4] * scale + p * bflo(vc.z);
            acc[5] = acc[5] * scale + p * bfhi(vc.z);
            acc[6] = acc[6] * scale + p * bflo(vc.w);
            acc[7] = acc[7] * scale + p * bfhi(vc.w);
            m = mnew;
        }
    }

    float inv = 1.f / (den + 1e-16f);
    size_t base = (size_t)d * HC + lane * 8;
    uint4 sv = *((const uint4*)(skipb + base));
    float sk[8] = { bflo(sv.x), bfhi(sv.x), bflo(sv.y), bfhi(sv.y),
                    bflo(sv.z), bfhi(sv.z), bflo(sv.w), bfhi(sv.w) };
    uint4 o;
    o.x = pack2(fmaxf(acc[0] * inv + sk[0], 0.f), fmaxf(acc[1] * inv + sk[1], 0.f));
    o.y = pack2(fmaxf(acc[2] * inv + sk[2], 0.f), fmaxf(acc[3] * inv + sk[3], 0.f));
    o.z = pack2(fmaxf(acc[4] * inv + sk[4], 0.f), fmaxf(acc[5] * inv + sk[5], 0.f));
    o.w = pack2(fmaxf(acc[6] * inv + sk[6], 0.f), fmaxf(acc[7] * inv + sk[7], 0.f));
    *(uint4*)(outb + base) = o;
}

// ---------------------------------------------------------------------------
extern "C" void kernel_launch(void* const* d_in, const int* in_sizes, int n_in,
                              void* d_out, int out_size, void* d_ws, size_t ws_size,
                              hipStream_t stream)
{
    const float* x   = (const float*)d_in[0];
    const int* ei    = (const int*)d_in[1];
    const int* esrc  = ei;
    const int* edst  = ei + NE;
    const float* q0w = (const float*)d_in[2];  const float* q0b = (const float*)d_in[3];
    const float* k0w = (const float*)d_in[4];  const float* k0b = (const float*)d_in[5];
    const float* v0w = (const float*)d_in[6];  const float* v0b = (const float*)d_in[7];
    const float* s0w = (const float*)d_in[8];  const float* s0b = (const float*)d_in[9];
    const float* q1w = (const float*)d_in[10]; const float* q1b = (const float*)d_in[11];
    const float* k1w = (const float*)d_in[12]; const float* k1b = (const float*)d_in[13];
    const float* v1w = (const float*)d_in[14]; const float* v1b = (const float*)d_in[15];
    const float* s1w = (const float*)d_in[16]; const float* s1b = (const float*)d_in[17];
    const float* ow  = (const float*)d_in[18]; const float* obs = (const float*)d_in[19];

    // ---- workspace (~247 MB) ----
    char* p = (char*)d_ws;
    auto take = [&](size_t bytes) { void* r = (void*)p; p += (bytes + 255) & ~(size_t)255; return r; };
    u16*   Qb     = (u16*)take((size_t)NN * HC * 2);       // 51.2 MB
    u16*   Vb     = (u16*)take((size_t)NN * HC * 2);       // 51.2 MB
    u16*   Hb     = (u16*)take((size_t)NN * HC * 2);       // 51.2 MB
    u16*   Sb     = (u16*)take((size_t)NN * HC * 2);       // 51.2 MB (bf16 skip)
    u16*   Xb     = (u16*)take((size_t)NN * DD * 2);       // 38.4 MB (bf16 x)
    u16*   Wc0    = (u16*)take((size_t)2048 * DD * 2);     // 1.57 MB
    u16*   Wc1    = (u16*)take((size_t)2048 * HC * 2);     // 2.10 MB
    u16*   WcO    = (u16*)take((size_t)DD * HC * 2);       // 0.39 MB
    float* barena = (float*)take(4480 * 4);                // 17.9 KB

    // ---- scratch carved from d_out (dead before final GEMM overwrites all) ----
    char* dob = (char*)d_out;
    u16* Kb       = (u16*)dob;                             // 51.2 MB
    int* deg      = (int*)(dob + 51200000);
    int* rowptr   = (int*)(dob + 51400192);                // NN+1
    int* cursor   = (int*)(dob + 51600384);
    int* esrc_ord = (int*)(dob + 51800576);                // 1.6 MB

    dim3 blk(256);
    int gN   = (NN + 255) / 256;
    int gE   = (NE + 255) / 256;
    int gnod = (NN + 3) / 4;
    const int NPAN = (NN + 127) / 128;   // 391 row panels
    int go = NPAN * 3;                   // out-proj: 3 col-tiles

    // ---- prep (2 launches) ----
    pack_bias<<<(4480 + 255) / 256, blk, 0, stream>>>(q0b, k0b, v0b, s0b,
                                                      q1b, k1b, v1b, s1b, obs, barena);
    cvt_all<<<(CVT_TOTAL + 255) / 256, blk, 0, stream>>>(x,
        q0w, k0w, v0w, s0w, q1w, k1w, v1w, s1w, ow, Xb, Wc0, Wc1, WcO);

    // ---- CSR build ----
    zero_deg      <<<gN, blk, 0, stream>>>(deg);
    hist_dst      <<<gE, blk, 0, stream>>>(edst, deg);
    scan_deg      <<<1, 1024, 0, stream>>>(deg, rowptr, cursor);
    scatter_edges <<<gE, blk, 0, stream>>>(esrc, edst, cursor, esrc_ord);

    // ---- layer 0 (A = Xb bf16, K=384) ----
    gemm_ws<DD><<<256, 512, 0, stream>>>(Xb, Wc0, barena, Qb, Kb, Vb, Sb);
    node_attn<<<gnod, blk, 0, stream>>>(Qb, Kb, Vb, rowptr, esrc_ord, Sb, Hb);

    // ---- layer 1 (A = Hb bf16, K=512) ----
    gemm_ws<HC><<<256, 512, 0, stream>>>(Hb, Wc1, barena + 2048, Qb, Kb, Vb, Sb);
    node_attn<<<gnod, blk, 0, stream>>>(Qb, Kb, Vb, rowptr, esrc_ord, Sb, Hb);

    // ---- output projection (fp32 out, overwrites ALL of d_out) ----
    gemm2ph<HC><<<go, blk, 0, stream>>>(Hb, WcO, barena + 4096,
                                        (float*)d_out, NN, 384, 3);
}

// Round 12
// 776.986 us; speedup vs baseline: 1.0449x; 1.0197x over previous
//
#include <hip/hip_runtime.h>
#include <hip/hip_bf16.h>

#define NN 50000   // nodes
#define NE 400000  // edges
#define DD 384     // input dim
#define HC 512     // heads * per-head dim (4 heads x 128)

typedef unsigned int u32;
typedef unsigned short u16;
typedef __attribute__((ext_vector_type(8))) short bf16x8;  // 8 bf16 (4 VGPRs)
typedef __attribute__((ext_vector_type(4))) float f32x4;

#define AS1 __attribute__((address_space(1)))
#define AS3 __attribute__((address_space(3)))

__device__ __forceinline__ float bflo(u32 u){ return __uint_as_float(u << 16); }
__device__ __forceinline__ float bfhi(u32 u){ return __uint_as_float(u & 0xFFFF0000u); }
__device__ __forceinline__ u16 f2bf(float f){
    u32 u = __float_as_uint(f);
    return (u16)((u + 0x7FFFu + ((u >> 16) & 1u)) >> 16);   // RNE
}
__device__ __forceinline__ u32 pack2(float a, float b){
    return (u32)f2bf(a) | ((u32)f2bf(b) << 16);
}

// ---------------------------------------------------------------------------
// Persistent weight-stationary QKVS GEMM, v4 — 64x64 wave tiles (0.5 LDS
// reads per MFMA, was 0.75), 8 waves (4 row x 2 col) over 256-row panels.
// Grid = 256 blocks x 512 threads; LDS = W 128x K wide rows (stationary,
// 96/128 KB) + A dbuf 2 x [256 rows][32k x 2B] (2 x 16 KB) = 160 KiB @K=512.
// Read patterns verified 2-way bank aliased (free): A row=64B slot=(kq+(row>>1))&3,
// W wide rows with 8-slot window XOR (r8-proven). Coalesced scalar epilogue
// (r8-proven; r11's packed-but-scattered stores regressed). stageA issued
// BEFORE the epilogue; vmcnt(63) on the 2 post-epilogue steps lets the 64
// stores retire in background instead of being drained by vmcnt(2).
// ---------------------------------------------------------------------------
template<int K>
__global__ __launch_bounds__(512)
void gemm_ws(const u16* __restrict__ Ab, const u16* __restrict__ Wb,
             const float* __restrict__ bias,
             u16* __restrict__ oQ, u16* __restrict__ oK,
             u16* __restrict__ oV, u16* __restrict__ oS)
{
    constexpr int NKC  = K / 32;        // 32-k chunks per panel (12 or 16)
    constexpr int WCH  = K / 8;         // 16B slots per W row
    constexpr int NPAN = (NN + 255) / 256;   // 196 big panels
    __shared__ char smW[128 * K * 2];   // wide rows, stride K*2 (bank-phase 0)
    __shared__ char smA[2][16384];      // [buf][256 rows][64 B]

    const int b   = blockIdx.x;
    const int xcd = b & 7;
    const int idx = b >> 3;
    const int ct  = idx & 15;           // col-tile (128 of 2048)
    const int rh  = idx >> 4;           // row-half of panel sequence

    const int tid  = threadIdx.x;
    const int lane = tid & 63;
    const int w    = tid >> 6;
    const int wr   = w >> 1;            // 0..3 -> 64-row slice
    const int wc   = w & 1;             // 0..1 -> 64-col slice
    const int r16  = lane & 15;
    const int kq   = lane >> 4;

    // ---- stage W once (gload_lds, 8-slot XOR per 128-B window) ----
    {
        const u16* W0 = Wb + (size_t)ct * 128 * K;
        #pragma unroll
        for (int p = 0; p < (128 * WCH) / 512; ++p) {
            int ci = p * 512 + tid;
            int row = ci / WCH, pc = ci % WCH;
            int lc = (pc & ~7) | ((pc ^ row) & 7);
            __builtin_amdgcn_global_load_lds((const AS1 u32*)(W0 + (size_t)row * K + lc * 8),
                                             (AS3 u32*)(smW + (size_t)ci * 16), 16, 0, 0);
        }
    }

    // ---- panel list p = (2j+rh)*8 + xcd over [0,196) ----
    int np = 0;
    while ((2 * np + rh) * 8 + xcd < NPAN) ++np;     // 12 or 13
    const int total = np * NKC;

    auto stageA = [&](int t) {                       // 2 gload_lds / thread
        int jp = t / NKC, kc = t - jp * NKC;
        int m0 = ((2 * jp + rh) * 8 + xcd) * 256;
        #pragma unroll
        for (int p = 0; p < 2; ++p) {
            int ci = p * 512 + tid;                  // 1024 chunks: 256 rows x 4 slots
            int row = ci >> 2, pc = ci & 3;
            int lc = (pc - (row >> 1)) & 3;          // inverse of read slot map
            int gr = m0 + row; if (gr >= NN) gr = NN - 1;
            __builtin_amdgcn_global_load_lds((const AS1 u32*)(Ab + (size_t)gr * K + kc * 32 + lc * 8),
                                             (AS3 u32*)(smA[t & 1] + ci * 16), 16, 0, 0);
        }
    };

    stageA(0);
    if (total > 1) stageA(1);

    f32x4 acc[4][4] = {};

    const int qsel = ct >> 2;
    u16* outp = (qsel == 0) ? oQ : (qsel == 1) ? oK : (qsel == 2) ? oV : oS;
    const int cb = (ct & 3) * 128 + wc * 64;
    float bv4[4];
    #pragma unroll
    for (int ni = 0; ni < 4; ++ni) bv4[ni] = bias[ct * 128 + wc * 64 + ni * 16 + r16];

    for (int t = 0; t < total; ++t) {
        const int jp = t / NKC, kc = t - jp * NKC;
        if (t + 1 >= total)          { asm volatile("s_waitcnt vmcnt(0)"  ::: "memory"); }
        else if (kc <= 1 && t > 1)   { asm volatile("s_waitcnt vmcnt(63)" ::: "memory"); }
        else                         { asm volatile("s_waitcnt vmcnt(2)"  ::: "memory"); }
        __builtin_amdgcn_s_barrier();          // stage(t) landed for all waves
        __builtin_amdgcn_sched_barrier(0);

        const char* bufA = smA[t & 1];
        const int c = kc * 4 + kq;             // global 16B slot in W row
        const int wbase = (c & ~7) << 4;
        bf16x8 av[4], bv[4];
        #pragma unroll
        for (int i = 0; i < 4; ++i) {
            int rowA = wr * 64 + i * 16 + r16;
            av[i] = *(const bf16x8*)(bufA + rowA * 64 + (((kq + (rowA >> 1)) & 3) << 4));
        }
        #pragma unroll
        for (int i = 0; i < 4; ++i) {
            int rowW = wc * 64 + i * 16 + r16;
            bv[i] = *(const bf16x8*)(smW + (size_t)rowW * (K * 2) + wbase
                                     + (((c ^ rowW) & 7) << 4));
        }
        #pragma unroll
        for (int mi = 0; mi < 4; ++mi)
            #pragma unroll
            for (int ni = 0; ni < 4; ++ni)
                acc[mi][ni] = __builtin_amdgcn_mfma_f32_16x16x32_bf16(
                    av[mi], bv[ni], acc[mi][ni], 0, 0, 0);

        __builtin_amdgcn_sched_barrier(0);
        __builtin_amdgcn_s_barrier();          // all waves done with buf t&1
        __builtin_amdgcn_sched_barrier(0);

        if (t + 2 < total) stageA(t + 2);      // issue BEFORE epilogue stores

        if (kc == NKC - 1) {                   // panel done: coalesced epilogue
            int m0 = ((2 * jp + rh) * 8 + xcd) * 256;
            #pragma unroll
            for (int mi = 0; mi < 4; ++mi) {
                #pragma unroll
                for (int ni = 0; ni < 4; ++ni) {
                    int col = cb + ni * 16 + r16;
                    float bb = bv4[ni];
                    #pragma unroll
                    for (int r = 0; r < 4; ++r) {
                        int gr = m0 + wr * 64 + mi * 16 + kq * 4 + r;
                        if (gr < NN) outp[(size_t)gr * 512 + col] = f2bf(acc[mi][ni][r] + bb);
                        acc[mi][ni][r] = 0.f;
                    }
                }
            }
        }
    }
}

// ---------------------------------------------------------------------------
// 2-deep pipelined MFMA GEMM — output projection (r7-proven form).
// ---------------------------------------------------------------------------
template<int K>
__global__ __launch_bounds__(256)
void gemm2ph(const u16* __restrict__ Ab, const u16* __restrict__ Wb,
             const float* __restrict__ bias, float* __restrict__ oF,
             int n, int Ototal, int NT)
{
    constexpr int NKT = K / 64;
    __shared__ char smA[2][16384];
    __shared__ char smB[2][16384];

    const int nb  = gridDim.x;
    const int bd  = blockIdx.x;
    const int q8  = nb >> 3, r8 = nb & 7;
    const int xcd = bd & 7, gg = bd >> 3;
    const int tt  = (xcd < r8 ? xcd * (q8 + 1) : r8 * (q8 + 1) + (xcd - r8) * q8) + gg;
    const int m0  = (tt / NT) * 128;
    const int o0  = (tt % NT) * 128;

    const int tid  = threadIdx.x;
    const int lane = tid & 63;
    const int w    = tid >> 6;
    const int wr   = w >> 1, wc = w & 1;
    const int r16  = lane & 15;
    const int kq   = lane >> 4;
    const int swz  = (r16 & 7) << 4;

    auto stage = [&](int bf, int kt) {
        #pragma unroll
        for (int p = 0; p < 4; ++p) {
            int ci = p * 256 + tid, row = ci >> 3, pc = ci & 7;
            int lc = pc ^ (row & 7);
            const u16* g = Wb + (size_t)(o0 + row) * K + kt * 64 + lc * 8;
            __builtin_amdgcn_global_load_lds((const AS1 u32*)g,
                                             (AS3 u32*)(smB[bf] + ci * 16), 16, 0, 0);
        }
        #pragma unroll
        for (int p = 0; p < 4; ++p) {
            int ci = p * 256 + tid, row = ci >> 3, pc = ci & 7;
            int lc = pc ^ (row & 7);
            int gr = m0 + row; if (gr >= n) gr = n - 1;
            const u16* g = Ab + (size_t)gr * K + kt * 64 + lc * 8;
            __builtin_amdgcn_global_load_lds((const AS1 u32*)g,
                                             (AS3 u32*)(smA[bf] + ci * 16), 16, 0, 0);
        }
    };

    f32x4 acc[4][4] = {};

    stage(0, 0);
    stage(1, 1);

    for (int kt = 0; kt < NKT; ++kt) {
        if (kt + 1 < NKT) { asm volatile("s_waitcnt vmcnt(8)" ::: "memory"); }
        else             { asm volatile("s_waitcnt vmcnt(0)" ::: "memory"); }
        __builtin_amdgcn_s_barrier();
        __builtin_amdgcn_sched_barrier(0);

        const char* pa = smA[kt & 1] + (wr * 64) * 128;
        const char* pb = smB[kt & 1] + (wc * 64) * 128;
        #pragma unroll
        for (int kk = 0; kk < 2; ++kk) {
            const int kb = kk * 64 + kq * 16;
            bf16x8 av[4], bv[4];
            #pragma unroll
            for (int i = 0; i < 4; ++i) {
                av[i] = *(const bf16x8*)(pa + (i * 16 + r16) * 128 + (kb ^ swz));
                bv[i] = *(const bf16x8*)(pb + (i * 16 + r16) * 128 + (kb ^ swz));
            }
            #pragma unroll
            for (int mi = 0; mi < 4; ++mi)
                #pragma unroll
                for (int ni = 0; ni < 4; ++ni)
                    acc[mi][ni] = __builtin_amdgcn_mfma_f32_16x16x32_bf16(
                        av[mi], bv[ni], acc[mi][ni], 0, 0, 0);
        }

        __builtin_amdgcn_sched_barrier(0);
        __builtin_amdgcn_s_barrier();
        __builtin_amdgcn_sched_barrier(0);
        if (kt + 2 < NKT) stage(kt & 1, kt + 2);
    }

    const int cbo = o0 + wc * 64;
    #pragma unroll
    for (int ni = 0; ni < 4; ++ni) {
        int col = cbo + ni * 16 + r16;
        float bb = bias[col];
        #pragma unroll
        for (int mi = 0; mi < 4; ++mi)
            #pragma unroll
            for (int r = 0; r < 4; ++r) {
                int gr = m0 + wr * 64 + mi * 16 + kq * 4 + r;
                if (gr < n) oF[(size_t)gr * Ototal + col] = acc[mi][ni][r] + bb;
            }
    }
}

// ---------------------------------------------------------------------------
// Fused fp32 -> bf16 conversion of x + all 9 weight matrices (one launch).
#define XG  2400000      // 50000*384/8
#define W0G 24576        // 512*384/8 per matrix
#define W1G 32768        // 512*512/8 per matrix
#define WOG 24576        // 384*512/8
#define CVT_TOTAL (XG + 4*W0G + 4*W1G + WOG)

__global__ __launch_bounds__(256)
void cvt_all(const float* __restrict__ x,
             const float* q0w, const float* k0w, const float* v0w, const float* s0w,
             const float* q1w, const float* k1w, const float* v1w, const float* s1w,
             const float* ow,
             u16* __restrict__ Xb, u16* __restrict__ Wc0,
             u16* __restrict__ Wc1, u16* __restrict__ WcO)
{
    int i = blockIdx.x * 256 + threadIdx.x;
    if (i >= CVT_TOTAL) return;
    const float* s; u16* d; int g;
    if (i < XG) { s = x; d = Xb; g = i; }
    else {
        int j = i - XG;
        if (j < 4 * W0G) {
            int q = j / W0G; g = j - q * W0G;
            s = (q == 0 ? q0w : q == 1 ? k0w : q == 2 ? v0w : s0w);
            d = Wc0 + (size_t)q * W0G * 8;
        } else if ((j -= 4 * W0G) < 4 * W1G) {
            int q = j / W1G; g = j - q * W1G;
            s = (q == 0 ? q1w : q == 1 ? k1w : q == 2 ? v1w : s1w);
            d = Wc1 + (size_t)q * W1G * 8;
        } else { j -= 4 * W1G; s = ow; d = WcO; g = j; }
    }
    float4 f0 = ((const float4*)s)[(size_t)g * 2];
    float4 f1 = ((const float4*)s)[(size_t)g * 2 + 1];
    uint4 o;
    o.x = pack2(f0.x, f0.y); o.y = pack2(f0.z, f0.w);
    o.z = pack2(f1.x, f1.y); o.w = pack2(f1.z, f1.w);
    ((uint4*)d)[g] = o;
}

// bias arena: [0..2047]=layer0 qkvs, [2048..4095]=layer1 qkvs, [4096..4479]=out
__global__ __launch_bounds__(256)
void pack_bias(const float* q0, const float* k0, const float* v0, const float* s0,
               const float* q1, const float* k1, const float* v1, const float* s1,
               const float* ob, float* __restrict__ dst)
{
    int i = blockIdx.x * 256 + threadIdx.x;
    if (i >= 4480) return;
    float v;
    if (i < 2048) {
        int j = i & 511, q = i >> 9;
        v = (q == 0 ? q0 : q == 1 ? k0 : q == 2 ? v0 : s0)[j];
    } else if (i < 4096) {
        int j = i - 2048; int q = j >> 9; j &= 511;
        v = (q == 0 ? q1 : q == 1 ? k1 : q == 2 ? v1 : s1)[j];
    } else {
        v = ob[i - 4096];
    }
    dst[i] = v;
}

// ---------------------------------------------------------------------------
// CSR build (order within bucket nondeterministic -> only permutes fp adds)
// ---------------------------------------------------------------------------
__global__ __launch_bounds__(256)
void zero_deg(int* __restrict__ deg)
{
    int i = blockIdx.x * 256 + threadIdx.x;
    if (i < NN) deg[i] = 0;
}

__global__ __launch_bounds__(256)
void hist_dst(const int* __restrict__ dst, int* __restrict__ deg)
{
    int e = blockIdx.x * 256 + threadIdx.x;
    if (e < NE) atomicAdd(&deg[dst[e]], 1);
}

// single-block scan, wave-shfl based
__global__ __launch_bounds__(1024)
void scan_deg(const int* __restrict__ deg, int* __restrict__ rowptr,
              int* __restrict__ cursor)
{
    __shared__ int wsum[16];
    const int tid = threadIdx.x, lane = tid & 63, wid = tid >> 6;
    int carry = 0;
    for (int base = 0; base < NN; base += 1024) {
        int i = base + tid;
        int orig = (i < NN) ? deg[i] : 0;
        int v = orig;
        #pragma unroll
        for (int off = 1; off < 64; off <<= 1) {
            int t = __shfl_up(v, off, 64);
            if (lane >= off) v += t;
        }
        if (lane == 63) wsum[wid] = v;
        __syncthreads();
        if (wid == 0) {
            int s = (lane < 16) ? wsum[lane] : 0;
            #pragma unroll
            for (int off = 1; off < 16; off <<= 1) {
                int t = __shfl_up(s, off, 16);
                if ((lane & 15) >= off) s += t;
            }
            if (lane < 16) wsum[lane] = s;
        }
        __syncthreads();
        int woff  = (wid == 0) ? 0 : wsum[wid - 1];
        int total = wsum[15];
        int excl  = carry + woff + (v - orig);
        if (i < NN) { rowptr[i] = excl; cursor[i] = excl; }
        carry += total;
        __syncthreads();
    }
    if (tid == 0) rowptr[NN] = NE;
}

__global__ __launch_bounds__(256)
void scatter_edges(const int* __restrict__ src, const int* __restrict__ dst,
                   int* __restrict__ cursor, int* __restrict__ esrc_ord)
{
    int e = blockIdx.x * 256 + threadIdx.x;
    if (e >= NE) return;
    int pos = atomicAdd(&cursor[dst[e]], 1);
    esrc_ord[pos] = src[e];
}

// ---------------------------------------------------------------------------
// Fused per-node attention with 1-edge software prefetch (r11-proven).
// ---------------------------------------------------------------------------
__global__ __launch_bounds__(256)
void node_attn(const u16* __restrict__ Qb, const u16* __restrict__ Kb,
               const u16* __restrict__ Vb, const int* __restrict__ rowptr,
               const int* __restrict__ esrc, const u16* __restrict__ skipb,
               u16* __restrict__ outb)
{
    int d = blockIdx.x * 4 + (threadIdx.x >> 6);
    if (d >= NN) return;
    int lane = threadIdx.x & 63;

    uint4 qv = *((const uint4*)(Qb + (size_t)d * HC) + lane);
    float q[8] = { bflo(qv.x), bfhi(qv.x), bflo(qv.y), bfhi(qv.y),
                   bflo(qv.z), bfhi(qv.z), bflo(qv.w), bfhi(qv.w) };

    int beg = rowptr[d], end = rowptr[d + 1];
    float m = -INFINITY, den = 0.f;
    float acc[8] = {};

    if (beg < end) {
        int s0 = esrc[beg];
        uint4 kv = *((const uint4*)(Kb + (size_t)s0 * HC) + lane);
        uint4 vv = *((const uint4*)(Vb + (size_t)s0 * HC) + lane);

        for (int i = beg; i < end; ++i) {
            uint4 kc = kv, vc = vv;
            if (i + 1 < end) {                   // prefetch next edge's rows
                int sn = esrc[i + 1];
                kv = *((const uint4*)(Kb + (size_t)sn * HC) + lane);
                vv = *((const uint4*)(Vb + (size_t)sn * HC) + lane);
            }
            float sum = q[0] * bflo(kc.x) + q[1] * bfhi(kc.x)
                      + q[2] * bflo(kc.y) + q[3] * bfhi(kc.y)
                      + q[4] * bflo(kc.z) + q[5] * bfhi(kc.z)
                      + q[6] * bflo(kc.w) + q[7] * bfhi(kc.w);
            #pragma unroll
            for (int off = 1; off < 16; off <<= 1) sum += __shfl_xor(sum, off, 64);
            float alpha = sum * 0.08838834764831845f;

            float mnew  = fmaxf(m, alpha);
            float scale = __expf(m - mnew);      // first edge: exp(-inf)=0
            float p     = __expf(alpha - mnew);
            den = den * scale + p;

            acc[0] = acc[0] * scale + p * bflo(vc.x);
            acc[1] = acc[1] * scale + p * bfhi(vc.x);
            acc[2] = acc[2] * scale + p * bflo(vc.y);
            acc[3] = acc[3] * scale + p * bfhi(vc.y);
            acc[4] = acc[4] * scale + p * bflo(vc.z);
            acc[5] = acc[5] * scale + p * bfhi(vc.z);
            acc[6] = acc[6] * scale + p * bflo(vc.w);
            acc[7] = acc[7] * scale + p * bfhi(vc.w);
            m = mnew;
        }
    }

    float inv = 1.f / (den + 1e-16f);
    size_t base = (size_t)d * HC + lane * 8;
    uint4 sv = *((const uint4*)(skipb + base));
    float sk[8] = { bflo(sv.x), bfhi(sv.x), bflo(sv.y), bfhi(sv.y),
                    bflo(sv.z), bfhi(sv.z), bflo(sv.w), bfhi(sv.w) };
    uint4 o;
    o.x = pack2(fmaxf(acc[0] * inv + sk[0], 0.f), fmaxf(acc[1] * inv + sk[1], 0.f));
    o.y = pack2(fmaxf(acc[2] * inv + sk[2], 0.f), fmaxf(acc[3] * inv + sk[3], 0.f));
    o.z = pack2(fmaxf(acc[4] * inv + sk[4], 0.f), fmaxf(acc[5] * inv + sk[5], 0.f));
    o.w = pack2(fmaxf(acc[6] * inv + sk[6], 0.f), fmaxf(acc[7] * inv + sk[7], 0.f));
    *(uint4*)(outb + base) = o;
}

// ---------------------------------------------------------------------------
extern "C" void kernel_launch(void* const* d_in, const int* in_sizes, int n_in,
                              void* d_out, int out_size, void* d_ws, size_t ws_size,
                              hipStream_t stream)
{
    const float* x   = (const float*)d_in[0];
    const int* ei    = (const int*)d_in[1];
    const int* esrc  = ei;
    const int* edst  = ei + NE;
    const float* q0w = (const float*)d_in[2];  const float* q0b = (const float*)d_in[3];
    const float* k0w = (const float*)d_in[4];  const float* k0b = (const float*)d_in[5];
    const float* v0w = (const float*)d_in[6];  const float* v0b = (const float*)d_in[7];
    const float* s0w = (const float*)d_in[8];  const float* s0b = (const float*)d_in[9];
    const float* q1w = (const float*)d_in[10]; const float* q1b = (const float*)d_in[11];
    const float* k1w = (const float*)d_in[12]; const float* k1b = (const float*)d_in[13];
    const float* v1w = (const float*)d_in[14]; const float* v1b = (const float*)d_in[15];
    const float* s1w = (const float*)d_in[16]; const float* s1b = (const float*)d_in[17];
    const float* ow  = (const float*)d_in[18]; const float* obs = (const float*)d_in[19];

    // ---- workspace (~247 MB) ----
    char* p = (char*)d_ws;
    auto take = [&](size_t bytes) { void* r = (void*)p; p += (bytes + 255) & ~(size_t)255; return r; };
    u16*   Qb     = (u16*)take((size_t)NN * HC * 2);       // 51.2 MB
    u16*   Vb     = (u16*)take((size_t)NN * HC * 2);       // 51.2 MB
    u16*   Hb     = (u16*)take((size_t)NN * HC * 2);       // 51.2 MB
    u16*   Sb     = (u16*)take((size_t)NN * HC * 2);       // 51.2 MB (bf16 skip)
    u16*   Xb     = (u16*)take((size_t)NN * DD * 2);       // 38.4 MB (bf16 x)
    u16*   Wc0    = (u16*)take((size_t)2048 * DD * 2);     // 1.57 MB
    u16*   Wc1    = (u16*)take((size_t)2048 * HC * 2);     // 2.10 MB
    u16*   WcO    = (u16*)take((size_t)DD * HC * 2);       // 0.39 MB
    float* barena = (float*)take(4480 * 4);                // 17.9 KB

    // ---- scratch carved from d_out (dead before final GEMM overwrites all) ----
    char* dob = (char*)d_out;
    u16* Kb       = (u16*)dob;                             // 51.2 MB
    int* deg      = (int*)(dob + 51200000);
    int* rowptr   = (int*)(dob + 51400192);                // NN+1
    int* cursor   = (int*)(dob + 51600384);
    int* esrc_ord = (int*)(dob + 51800576);                // 1.6 MB

    dim3 blk(256);
    int gN   = (NN + 255) / 256;
    int gE   = (NE + 255) / 256;
    int gnod = (NN + 3) / 4;
    const int NPAN = (NN + 127) / 128;   // 391 row panels (out-proj)
    int go = NPAN * 3;                   // out-proj: 3 col-tiles

    // ---- prep (2 launches) ----
    pack_bias<<<(4480 + 255) / 256, blk, 0, stream>>>(q0b, k0b, v0b, s0b,
                                                      q1b, k1b, v1b, s1b, obs, barena);
    cvt_all<<<(CVT_TOTAL + 255) / 256, blk, 0, stream>>>(x,
        q0w, k0w, v0w, s0w, q1w, k1w, v1w, s1w, ow, Xb, Wc0, Wc1, WcO);

    // ---- CSR build ----
    zero_deg      <<<gN, blk, 0, stream>>>(deg);
    hist_dst      <<<gE, blk, 0, stream>>>(edst, deg);
    scan_deg      <<<1, 1024, 0, stream>>>(deg, rowptr, cursor);
    scatter_edges <<<gE, blk, 0, stream>>>(esrc, edst, cursor, esrc_ord);

    // ---- layer 0 (A = Xb bf16, K=384) ----
    gemm_ws<DD><<<256, 512, 0, stream>>>(Xb, Wc0, barena, Qb, Kb, Vb, Sb);
    node_attn<<<gnod, blk, 0, stream>>>(Qb, Kb, Vb, rowptr, esrc_ord, Sb, Hb);

    // ---- layer 1 (A = Hb bf16, K=512) ----
    gemm_ws<HC><<<256, 512, 0, stream>>>(Hb, Wc1, barena + 2048, Qb, Kb, Vb, Sb);
    node_attn<<<gnod, blk, 0, stream>>>(Qb, Kb, Vb, rowptr, esrc_ord, Sb, Hb);

    // ---- output projection (fp32 out, overwrites ALL of d_out) ----
    gemm2ph<HC><<<go, blk, 0, stream>>>(Hb, WcO, barena + 4096,
                                        (float*)d_out, NN, 384, 3);
}

// Round 13
// 716.589 us; speedup vs baseline: 1.1329x; 1.0843x over previous
//
#include <hip/hip_runtime.h>
#include <hip/hip_bf16.h>

#define NN 50000   // nodes
#define NE 400000  // edges
#define DD 384     // input dim
#define HC 512     // heads * per-head dim (4 heads x 128)

typedef unsigned int u32;
typedef unsigned short u16;
typedef __attribute__((ext_vector_type(8))) short bf16x8;  // 8 bf16 (4 VGPRs)
typedef __attribute__((ext_vector_type(4))) float f32x4;

#define AS1 __attribute__((address_space(1)))
#define AS3 __attribute__((address_space(3)))

__device__ __forceinline__ float bflo(u32 u){ return __uint_as_float(u << 16); }
__device__ __forceinline__ float bfhi(u32 u){ return __uint_as_float(u & 0xFFFF0000u); }
__device__ __forceinline__ u16 f2bf(float f){
    u32 u = __float_as_uint(f);
    return (u16)((u + 0x7FFFu + ((u >> 16) & 1u)) >> 16);   // RNE
}
__device__ __forceinline__ u32 pack2(float a, float b){
    return (u32)f2bf(a) | ((u32)f2bf(b) << 16);
}
__device__ __forceinline__ float dot8(const float* q, uint4 k){
    return q[0] * bflo(k.x) + q[1] * bfhi(k.x)
         + q[2] * bflo(k.y) + q[3] * bfhi(k.y)
         + q[4] * bflo(k.z) + q[5] * bfhi(k.z)
         + q[6] * bflo(k.w) + q[7] * bfhi(k.w);
}

// ---------------------------------------------------------------------------
// Persistent weight-stationary QKVS GEMM — BYTE-EXACT round-8 version
// (best measured of 5 variants: 176us; r9-r12 redesigns all regressed).
// Grid = 256 blocks (1/CU, 160 KB LDS), 512 threads = 8 waves.
// W[ct*128..+128)[K] staged to LDS ONCE (wide rows, 8-slot XOR window);
// A panels stream through 2x16 KB dbuf with counted vmcnt(2), ~200-step pipe.
// ---------------------------------------------------------------------------
template<int K>
__global__ __launch_bounds__(512)
void gemm_ws(const u16* __restrict__ Ab, const u16* __restrict__ Wb,
             const float* __restrict__ bias,
             u16* __restrict__ oQ, u16* __restrict__ oK,
             u16* __restrict__ oV, u16* __restrict__ oS)
{
    constexpr int NKT  = K / 64;        // A k-chunks per panel
    constexpr int WCH  = K / 8;         // 16B chunks per W row
    constexpr int NPAN = (NN + 127) / 128;
    __shared__ char smW[128 * K * 2];   // 128 KB @K=512, 96 KB @K=384
    __shared__ char smA[2][16384];      // [buf][128 rows][64 k x 2B]

    const int b   = blockIdx.x;
    const int xcd = b & 7;
    const int idx = b >> 3;
    const int ct  = idx & 15;           // col-tile (128 cols of 2048)
    const int rh  = idx >> 4;           // row-half (0/1)

    const int tid  = threadIdx.x;
    const int lane = tid & 63;
    const int w    = tid >> 6;
    const int wq   = w >> 1;            // row quarter 0..3 (32 rows)
    const int wc   = w & 1;             // col half 0..1 (64 cols)
    const int r16  = lane & 15;
    const int kq   = lane >> 4;

    // ---- stage W once ----
    const u16* Wrow0 = Wb + (size_t)ct * 128 * K;
    #pragma unroll
    for (int p = 0; p < (128 * WCH) / 512; ++p) {
        int ci = p * 512 + tid;
        int row = ci / WCH, pc = ci % WCH;
        int lc = (pc & ~7) | ((pc ^ row) & 7);
        __builtin_amdgcn_global_load_lds((const AS1 u32*)(Wrow0 + (size_t)row * K + lc * 8),
                                         (AS3 u32*)(smW + (size_t)ci * 16), 16, 0, 0);
    }

    // ---- panel list: p = (2j+rh)*8 + xcd ----
    auto panel = [&](int j) { return (2 * j + rh) * 8 + xcd; };
    int np = 0;
    while (panel(np) < NPAN) ++np;      // 24 or 25
    const int total = np * NKT;

    // A stage: 1024 chunks over 512 threads -> 2 gload_lds/thread
    auto stageA = [&](int t) {
        int j = t / NKT, kc = t - (t / NKT) * NKT;
        int m0 = panel(j) * 128;
        #pragma unroll
        for (int p = 0; p < 2; ++p) {
            int ci = p * 512 + tid;
            int row = ci >> 3, pc = ci & 7;
            int lc = pc ^ (row & 7);
            int gr = m0 + row; if (gr >= NN) gr = NN - 1;
            __builtin_amdgcn_global_load_lds((const AS1 u32*)(Ab + (size_t)gr * K + kc * 64 + lc * 8),
                                             (AS3 u32*)(smA[t & 1] + ci * 16), 16, 0, 0);
        }
    };

    stageA(0);
    stageA(1);

    f32x4 acc[2][4] = {};

    const int qsel = ct >> 2;
    u16* outp = (qsel == 0) ? oQ : (qsel == 1) ? oK : (qsel == 2) ? oV : oS;
    const int cb = (ct & 3) * 128 + wc * 64;
    float bv4[4];
    #pragma unroll
    for (int ni = 0; ni < 4; ++ni) bv4[ni] = bias[ct * 128 + wc * 64 + ni * 16 + r16];

    for (int t = 0; t < total; ++t) {
        if (t + 1 < total) { asm volatile("s_waitcnt vmcnt(2)" ::: "memory"); }
        else               { asm volatile("s_waitcnt vmcnt(0)" ::: "memory"); }
        __builtin_amdgcn_s_barrier();          // stage(t) landed for all waves
        __builtin_amdgcn_sched_barrier(0);

        const int jj = t / NKT;
        const int kt = t - jj * NKT;
        const char* bufA = smA[t & 1];
        #pragma unroll
        for (int kk = 0; kk < 2; ++kk) {
            bf16x8 av[2], bv[4];
            #pragma unroll
            for (int i = 0; i < 2; ++i) {
                int rowA = wq * 32 + i * 16 + r16;
                int c = kk * 4 + kq;
                av[i] = *(const bf16x8*)(bufA + rowA * 128 + ((c ^ (rowA & 7)) << 4));
            }
            #pragma unroll
            for (int i = 0; i < 4; ++i) {
                int rowW = wc * 64 + i * 16 + r16;
                int c = kt * 8 + kk * 4 + kq;
                int pcw = (c & ~7) | ((c ^ rowW) & 7);
                bv[i] = *(const bf16x8*)(smW + (size_t)rowW * (K * 2) + (pcw << 4));
            }
            #pragma unroll
            for (int mi = 0; mi < 2; ++mi)
                #pragma unroll
                for (int ni = 0; ni < 4; ++ni)
                    acc[mi][ni] = __builtin_amdgcn_mfma_f32_16x16x32_bf16(
                        av[mi], bv[ni], acc[mi][ni], 0, 0, 0);
        }

        __builtin_amdgcn_sched_barrier(0);
        __builtin_amdgcn_s_barrier();          // all waves done reading buf t&1
        __builtin_amdgcn_sched_barrier(0);

        if (kt == NKT - 1) {                   // panel finished: epilogue
            int m0 = panel(jj) * 128;
            #pragma unroll
            for (int ni = 0; ni < 4; ++ni) {
                int col = cb + ni * 16 + r16;
                float bb = bv4[ni];
                #pragma unroll
                for (int mi = 0; mi < 2; ++mi)
                    #pragma unroll
                    for (int r = 0; r < 4; ++r) {
                        int gr = m0 + wq * 32 + mi * 16 + kq * 4 + r;
                        if (gr < NN) outp[(size_t)gr * 512 + col] = f2bf(acc[mi][ni][r] + bb);
                        acc[mi][ni][r] = 0.f;
                    }
            }
        }
        if (t + 2 < total) stageA(t + 2);      // overwrite now-free buffer
    }
}

// ---------------------------------------------------------------------------
// 2-deep pipelined MFMA GEMM — output projection (r7-proven form).
// ---------------------------------------------------------------------------
template<int K>
__global__ __launch_bounds__(256)
void gemm2ph(const u16* __restrict__ Ab, const u16* __restrict__ Wb,
             const float* __restrict__ bias, float* __restrict__ oF,
             int n, int Ototal, int NT)
{
    constexpr int NKT = K / 64;
    __shared__ char smA[2][16384];
    __shared__ char smB[2][16384];

    const int nb  = gridDim.x;
    const int bd  = blockIdx.x;
    const int q8  = nb >> 3, r8 = nb & 7;
    const int xcd = bd & 7, gg = bd >> 3;
    const int tt  = (xcd < r8 ? xcd * (q8 + 1) : r8 * (q8 + 1) + (xcd - r8) * q8) + gg;
    const int m0  = (tt / NT) * 128;
    const int o0  = (tt % NT) * 128;

    const int tid  = threadIdx.x;
    const int lane = tid & 63;
    const int w    = tid >> 6;
    const int wr   = w >> 1, wc = w & 1;
    const int r16  = lane & 15;
    const int kq   = lane >> 4;
    const int swz  = (r16 & 7) << 4;

    auto stage = [&](int bf, int kt) {
        #pragma unroll
        for (int p = 0; p < 4; ++p) {
            int ci = p * 256 + tid, row = ci >> 3, pc = ci & 7;
            int lc = pc ^ (row & 7);
            const u16* g = Wb + (size_t)(o0 + row) * K + kt * 64 + lc * 8;
            __builtin_amdgcn_global_load_lds((const AS1 u32*)g,
                                             (AS3 u32*)(smB[bf] + ci * 16), 16, 0, 0);
        }
        #pragma unroll
        for (int p = 0; p < 4; ++p) {
            int ci = p * 256 + tid, row = ci >> 3, pc = ci & 7;
            int lc = pc ^ (row & 7);
            int gr = m0 + row; if (gr >= n) gr = n - 1;
            const u16* g = Ab + (size_t)gr * K + kt * 64 + lc * 8;
            __builtin_amdgcn_global_load_lds((const AS1 u32*)g,
                                             (AS3 u32*)(smA[bf] + ci * 16), 16, 0, 0);
        }
    };

    f32x4 acc[4][4] = {};

    stage(0, 0);
    stage(1, 1);

    for (int kt = 0; kt < NKT; ++kt) {
        if (kt + 1 < NKT) { asm volatile("s_waitcnt vmcnt(8)" ::: "memory"); }
        else             { asm volatile("s_waitcnt vmcnt(0)" ::: "memory"); }
        __builtin_amdgcn_s_barrier();
        __builtin_amdgcn_sched_barrier(0);

        const char* pa = smA[kt & 1] + (wr * 64) * 128;
        const char* pb = smB[kt & 1] + (wc * 64) * 128;
        #pragma unroll
        for (int kk = 0; kk < 2; ++kk) {
            const int kb = kk * 64 + kq * 16;
            bf16x8 av[4], bv[4];
            #pragma unroll
            for (int i = 0; i < 4; ++i) {
                av[i] = *(const bf16x8*)(pa + (i * 16 + r16) * 128 + (kb ^ swz));
                bv[i] = *(const bf16x8*)(pb + (i * 16 + r16) * 128 + (kb ^ swz));
            }
            #pragma unroll
            for (int mi = 0; mi < 4; ++mi)
                #pragma unroll
                for (int ni = 0; ni < 4; ++ni)
                    acc[mi][ni] = __builtin_amdgcn_mfma_f32_16x16x32_bf16(
                        av[mi], bv[ni], acc[mi][ni], 0, 0, 0);
        }

        __builtin_amdgcn_sched_barrier(0);
        __builtin_amdgcn_s_barrier();
        __builtin_amdgcn_sched_barrier(0);
        if (kt + 2 < NKT) stage(kt & 1, kt + 2);
    }

    const int cbo = o0 + wc * 64;
    #pragma unroll
    for (int ni = 0; ni < 4; ++ni) {
        int col = cbo + ni * 16 + r16;
        float bb = bias[col];
        #pragma unroll
        for (int mi = 0; mi < 4; ++mi)
            #pragma unroll
            for (int r = 0; r < 4; ++r) {
                int gr = m0 + wr * 64 + mi * 16 + kq * 4 + r;
                if (gr < n) oF[(size_t)gr * Ototal + col] = acc[mi][ni][r] + bb;
            }
    }
}

// ---------------------------------------------------------------------------
// Fused fp32 -> bf16 conversion of x + all 9 weight matrices (one launch).
#define XG  2400000      // 50000*384/8
#define W0G 24576        // 512*384/8 per matrix
#define W1G 32768        // 512*512/8 per matrix
#define WOG 24576        // 384*512/8
#define CVT_TOTAL (XG + 4*W0G + 4*W1G + WOG)

__global__ __launch_bounds__(256)
void cvt_all(const float* __restrict__ x,
             const float* q0w, const float* k0w, const float* v0w, const float* s0w,
             const float* q1w, const float* k1w, const float* v1w, const float* s1w,
             const float* ow,
             u16* __restrict__ Xb, u16* __restrict__ Wc0,
             u16* __restrict__ Wc1, u16* __restrict__ WcO)
{
    int i = blockIdx.x * 256 + threadIdx.x;
    if (i >= CVT_TOTAL) return;
    const float* s; u16* d; int g;
    if (i < XG) { s = x; d = Xb; g = i; }
    else {
        int j = i - XG;
        if (j < 4 * W0G) {
            int q = j / W0G; g = j - q * W0G;
            s = (q == 0 ? q0w : q == 1 ? k0w : q == 2 ? v0w : s0w);
            d = Wc0 + (size_t)q * W0G * 8;
        } else if ((j -= 4 * W0G) < 4 * W1G) {
            int q = j / W1G; g = j - q * W1G;
            s = (q == 0 ? q1w : q == 1 ? k1w : q == 2 ? v1w : s1w);
            d = Wc1 + (size_t)q * W1G * 8;
        } else { j -= 4 * W1G; s = ow; d = WcO; g = j; }
    }
    float4 f0 = ((const float4*)s)[(size_t)g * 2];
    float4 f1 = ((const float4*)s)[(size_t)g * 2 + 1];
    uint4 o;
    o.x = pack2(f0.x, f0.y); o.y = pack2(f0.z, f0.w);
    o.z = pack2(f1.x, f1.y); o.w = pack2(f1.z, f1.w);
    ((uint4*)d)[g] = o;
}

// bias arena: [0..2047]=layer0 qkvs, [2048..4095]=layer1 qkvs, [4096..4479]=out
__global__ __launch_bounds__(256)
void pack_bias(const float* q0, const float* k0, const float* v0, const float* s0,
               const float* q1, const float* k1, const float* v1, const float* s1,
               const float* ob, float* __restrict__ dst)
{
    int i = blockIdx.x * 256 + threadIdx.x;
    if (i >= 4480) return;
    float v;
    if (i < 2048) {
        int j = i & 511, q = i >> 9;
        v = (q == 0 ? q0 : q == 1 ? k0 : q == 2 ? v0 : s0)[j];
    } else if (i < 4096) {
        int j = i - 2048; int q = j >> 9; j &= 511;
        v = (q == 0 ? q1 : q == 1 ? k1 : q == 2 ? v1 : s1)[j];
    } else {
        v = ob[i - 4096];
    }
    dst[i] = v;
}

// ---------------------------------------------------------------------------
// CSR build (order within bucket nondeterministic -> only permutes fp adds)
// ---------------------------------------------------------------------------
__global__ __launch_bounds__(256)
void zero_deg(int* __restrict__ deg)
{
    int i = blockIdx.x * 256 + threadIdx.x;
    if (i < NN) deg[i] = 0;
}

__global__ __launch_bounds__(256)
void hist_dst(const int* __restrict__ dst, int* __restrict__ deg)
{
    int e = blockIdx.x * 256 + threadIdx.x;
    if (e < NE) atomicAdd(&deg[dst[e]], 1);
}

// single-block scan, wave-shfl based
__global__ __launch_bounds__(1024)
void scan_deg(const int* __restrict__ deg, int* __restrict__ rowptr,
              int* __restrict__ cursor)
{
    __shared__ int wsum[16];
    const int tid = threadIdx.x, lane = tid & 63, wid = tid >> 6;
    int carry = 0;
    for (int base = 0; base < NN; base += 1024) {
        int i = base + tid;
        int orig = (i < NN) ? deg[i] : 0;
        int v = orig;
        #pragma unroll
        for (int off = 1; off < 64; off <<= 1) {
            int t = __shfl_up(v, off, 64);
            if (lane >= off) v += t;
        }
        if (lane == 63) wsum[wid] = v;
        __syncthreads();
        if (wid == 0) {
            int s = (lane < 16) ? wsum[lane] : 0;
            #pragma unroll
            for (int off = 1; off < 16; off <<= 1) {
                int t = __shfl_up(s, off, 16);
                if ((lane & 15) >= off) s += t;
            }
            if (lane < 16) wsum[lane] = s;
        }
        __syncthreads();
        int woff  = (wid == 0) ? 0 : wsum[wid - 1];
        int total = wsum[15];
        int excl  = carry + woff + (v - orig);
        if (i < NN) { rowptr[i] = excl; cursor[i] = excl; }
        carry += total;
        __syncthreads();
    }
    if (tid == 0) rowptr[NN] = NE;
}

__global__ __launch_bounds__(256)
void scatter_edges(const int* __restrict__ src, const int* __restrict__ dst,
                   int* __restrict__ cursor, int* __restrict__ esrc_ord)
{
    int e = blockIdx.x * 256 + threadIdx.x;
    if (e >= NE) return;
    int pos = atomicAdd(&cursor[dst[e]], 1);
    esrc_ord[pos] = src[e];
}

// ---------------------------------------------------------------------------
// Fused per-node attention, 2-edge unrolled + pair prefetch: one wave per dst
// node; online softmax. Two independent shfl-reduce chains per iteration
// overlap their latency; K/V rows of the NEXT pair load during compute.
// Pairwise max update is order-equivalent within fp tolerance.
// ---------------------------------------------------------------------------
__global__ __launch_bounds__(256)
void node_attn(const u16* __restrict__ Qb, const u16* __restrict__ Kb,
               const u16* __restrict__ Vb, const int* __restrict__ rowptr,
               const int* __restrict__ esrc, const u16* __restrict__ skipb,
               u16* __restrict__ outb)
{
    int d = blockIdx.x * 4 + (threadIdx.x >> 6);
    if (d >= NN) return;
    int lane = threadIdx.x & 63;

    uint4 qv = *((const uint4*)(Qb + (size_t)d * HC) + lane);
    float q[8] = { bflo(qv.x), bfhi(qv.x), bflo(qv.y), bfhi(qv.y),
                   bflo(qv.z), bfhi(qv.z), bflo(qv.w), bfhi(qv.w) };

    int beg = rowptr[d], end = rowptr[d + 1];
    int cnt = end - beg;
    float m = -INFINITY, den = 0.f;
    float acc[8] = {};

    uint4 k0, v0, k1, v1;
    if (cnt > 0) {
        int s = esrc[beg];
        k0 = *((const uint4*)(Kb + (size_t)s * HC) + lane);
        v0 = *((const uint4*)(Vb + (size_t)s * HC) + lane);
    }
    if (cnt > 1) {
        int s = esrc[beg + 1];
        k1 = *((const uint4*)(Kb + (size_t)s * HC) + lane);
        v1 = *((const uint4*)(Vb + (size_t)s * HC) + lane);
    }

    int i = beg;
    for (; i + 1 < end; i += 2) {
        uint4 ka = k0, va = v0, kb = k1, vb = v1;
        if (i + 2 < end) {                       // prefetch next pair
            int s = esrc[i + 2];
            k0 = *((const uint4*)(Kb + (size_t)s * HC) + lane);
            v0 = *((const uint4*)(Vb + (size_t)s * HC) + lane);
        }
        if (i + 3 < end) {
            int s = esrc[i + 3];
            k1 = *((const uint4*)(Kb + (size_t)s * HC) + lane);
            v1 = *((const uint4*)(Vb + (size_t)s * HC) + lane);
        }
        float s0 = dot8(q, ka);
        float s1 = dot8(q, kb);
        #pragma unroll
        for (int off = 1; off < 16; off <<= 1) {   // two chains interleave
            s0 += __shfl_xor(s0, off, 64);
            s1 += __shfl_xor(s1, off, 64);
        }
        float a0 = s0 * 0.08838834764831845f;
        float a1 = s1 * 0.08838834764831845f;

        float mnew  = fmaxf(m, fmaxf(a0, a1));
        float scale = __expf(m - mnew);
        float p0    = __expf(a0 - mnew);
        float p1    = __expf(a1 - mnew);
        den = den * scale + p0 + p1;

        acc[0] = acc[0] * scale + p0 * bflo(va.x) + p1 * bflo(vb.x);
        acc[1] = acc[1] * scale + p0 * bfhi(va.x) + p1 * bfhi(vb.x);
        acc[2] = acc[2] * scale + p0 * bflo(va.y) + p1 * bflo(vb.y);
        acc[3] = acc[3] * scale + p0 * bfhi(va.y) + p1 * bfhi(vb.y);
        acc[4] = acc[4] * scale + p0 * bflo(va.z) + p1 * bflo(vb.z);
        acc[5] = acc[5] * scale + p0 * bfhi(va.z) + p1 * bfhi(vb.z);
        acc[6] = acc[6] * scale + p0 * bflo(va.w) + p1 * bflo(vb.w);
        acc[7] = acc[7] * scale + p0 * bfhi(va.w) + p1 * bfhi(vb.w);
        m = mnew;
    }
    if (i < end) {                               // odd tail: edge lives in k0/v0
        float s0 = dot8(q, k0);
        #pragma unroll
        for (int off = 1; off < 16; off <<= 1) s0 += __shfl_xor(s0, off, 64);
        float a0 = s0 * 0.08838834764831845f;
        float mnew  = fmaxf(m, a0);
        float scale = __expf(m - mnew);
        float p0    = __expf(a0 - mnew);
        den = den * scale + p0;
        acc[0] = acc[0] * scale + p0 * bflo(v0.x);
        acc[1] = acc[1] * scale + p0 * bfhi(v0.x);
        acc[2] = acc[2] * scale + p0 * bflo(v0.y);
        acc[3] = acc[3] * scale + p0 * bfhi(v0.y);
        acc[4] = acc[4] * scale + p0 * bflo(v0.z);
        acc[5] = acc[5] * scale + p0 * bfhi(v0.z);
        acc[6] = acc[6] * scale + p0 * bflo(v0.w);
        acc[7] = acc[7] * scale + p0 * bfhi(v0.w);
    }

    float inv = 1.f / (den + 1e-16f);
    size_t base = (size_t)d * HC + lane * 8;
    uint4 sv = *((const uint4*)(skipb + base));
    float sk[8] = { bflo(sv.x), bfhi(sv.x), bflo(sv.y), bfhi(sv.y),
                    bflo(sv.z), bfhi(sv.z), bflo(sv.w), bfhi(sv.w) };
    uint4 o;
    o.x = pack2(fmaxf(acc[0] * inv + sk[0], 0.f), fmaxf(acc[1] * inv + sk[1], 0.f));
    o.y = pack2(fmaxf(acc[2] * inv + sk[2], 0.f), fmaxf(acc[3] * inv + sk[3], 0.f));
    o.z = pack2(fmaxf(acc[4] * inv + sk[4], 0.f), fmaxf(acc[5] * inv + sk[5], 0.f));
    o.w = pack2(fmaxf(acc[6] * inv + sk[6], 0.f), fmaxf(acc[7] * inv + sk[7], 0.f));
    *(uint4*)(outb + base) = o;
}

// ---------------------------------------------------------------------------
extern "C" void kernel_launch(void* const* d_in, const int* in_sizes, int n_in,
                              void* d_out, int out_size, void* d_ws, size_t ws_size,
                              hipStream_t stream)
{
    const float* x   = (const float*)d_in[0];
    const int* ei    = (const int*)d_in[1];
    const int* esrc  = ei;
    const int* edst  = ei + NE;
    const float* q0w = (const float*)d_in[2];  const float* q0b = (const float*)d_in[3];
    const float* k0w = (const float*)d_in[4];  const float* k0b = (const float*)d_in[5];
    const float* v0w = (const float*)d_in[6];  const float* v0b = (const float*)d_in[7];
    const float* s0w = (const float*)d_in[8];  const float* s0b = (const float*)d_in[9];
    const float* q1w = (const float*)d_in[10]; const float* q1b = (const float*)d_in[11];
    const float* k1w = (const float*)d_in[12]; const float* k1b = (const float*)d_in[13];
    const float* v1w = (const float*)d_in[14]; const float* v1b = (const float*)d_in[15];
    const float* s1w = (const float*)d_in[16]; const float* s1b = (const float*)d_in[17];
    const float* ow  = (const float*)d_in[18]; const float* obs = (const float*)d_in[19];

    // ---- workspace (~247 MB) ----
    char* p = (char*)d_ws;
    auto take = [&](size_t bytes) { void* r = (void*)p; p += (bytes + 255) & ~(size_t)255; return r; };
    u16*   Qb     = (u16*)take((size_t)NN * HC * 2);       // 51.2 MB
    u16*   Vb     = (u16*)take((size_t)NN * HC * 2);       // 51.2 MB
    u16*   Hb     = (u16*)take((size_t)NN * HC * 2);       // 51.2 MB
    u16*   Sb     = (u16*)take((size_t)NN * HC * 2);       // 51.2 MB (bf16 skip)
    u16*   Xb     = (u16*)take((size_t)NN * DD * 2);       // 38.4 MB (bf16 x)
    u16*   Wc0    = (u16*)take((size_t)2048 * DD * 2);     // 1.57 MB
    u16*   Wc1    = (u16*)take((size_t)2048 * HC * 2);     // 2.10 MB
    u16*   WcO    = (u16*)take((size_t)DD * HC * 2);       // 0.39 MB
    float* barena = (float*)take(4480 * 4);                // 17.9 KB

    // ---- scratch carved from d_out (dead before final GEMM overwrites all) ----
    char* dob = (char*)d_out;
    u16* Kb       = (u16*)dob;                             // 51.2 MB
    int* deg      = (int*)(dob + 51200000);
    int* rowptr   = (int*)(dob + 51400192);                // NN+1
    int* cursor   = (int*)(dob + 51600384);
    int* esrc_ord = (int*)(dob + 51800576);                // 1.6 MB

    dim3 blk(256);
    int gN   = (NN + 255) / 256;
    int gE   = (NE + 255) / 256;
    int gnod = (NN + 3) / 4;
    const int NPAN = (NN + 127) / 128;   // 391 row panels (out-proj)
    int go = NPAN * 3;                   // out-proj: 3 col-tiles

    // ---- prep (2 launches) ----
    pack_bias<<<(4480 + 255) / 256, blk, 0, stream>>>(q0b, k0b, v0b, s0b,
                                                      q1b, k1b, v1b, s1b, obs, barena);
    cvt_all<<<(CVT_TOTAL + 255) / 256, blk, 0, stream>>>(x,
        q0w, k0w, v0w, s0w, q1w, k1w, v1w, s1w, ow, Xb, Wc0, Wc1, WcO);

    // ---- CSR build ----
    zero_deg      <<<gN, blk, 0, stream>>>(deg);
    hist_dst      <<<gE, blk, 0, stream>>>(edst, deg);
    scan_deg      <<<1, 1024, 0, stream>>>(deg, rowptr, cursor);
    scatter_edges <<<gE, blk, 0, stream>>>(esrc, edst, cursor, esrc_ord);

    // ---- layer 0 (A = Xb bf16, K=384) ----
    gemm_ws<DD><<<256, 512, 0, stream>>>(Xb, Wc0, barena, Qb, Kb, Vb, Sb);
    node_attn<<<gnod, blk, 0, stream>>>(Qb, Kb, Vb, rowptr, esrc_ord, Sb, Hb);

    // ---- layer 1 (A = Hb bf16, K=512) ----
    gemm_ws<HC><<<256, 512, 0, stream>>>(Hb, Wc1, barena + 2048, Qb, Kb, Vb, Sb);
    node_attn<<<gnod, blk, 0, stream>>>(Qb, Kb, Vb, rowptr, esrc_ord, Sb, Hb);

    // ---- output projection (fp32 out, overwrites ALL of d_out) ----
    gemm2ph<HC><<<go, blk, 0, stream>>>(Hb, WcO, barena + 4096,
                                        (float*)d_out, NN, 384, 3);
}